// Round 2
// baseline (698.505 us; speedup 1.0000x reference)
//
#include <hip/hip_runtime.h>
#include <math.h>

#define BB 32
#define SS 65536
#define CC 20
#define NM 16
#define HH 128
#define RP 264   // DFT LDS row pitch (bf16 elems)
#define WP 64    // hT row pitch (bf16 elems): 8x short8 payload, XOR-swizzled chunks
#define NSLOT 16

using short8  = __attribute__((ext_vector_type(8))) short;
using floatx4 = __attribute__((ext_vector_type(4))) float;

__device__ __forceinline__ unsigned short f2bf(float f) {
    union { float f; unsigned u; } v; v.f = f;
    unsigned u = v.u;
    return (unsigned short)((u + 0x7FFFu + ((u >> 16) & 1u)) >> 16);   // RNE
}
__device__ __forceinline__ float bf2f(unsigned short h) {
    union { unsigned u; float f; } v; v.u = ((unsigned)h) << 16; return v.f;
}
__device__ __forceinline__ unsigned short f2bflo(float a) {
    return f2bf(a - bf2f(f2bf(a)));
}

// Tanh-form gelu, native exp2/rcp (R11). |delta| vs erf-gelu ~3e-4.
// NOTE (R15 lesson): keep all WEIGHT reads as scalar float loads — vector-
// typed (float2/float4) loads from uniform addresses defeat s_load
// scalarization and regress 2.3x.
__device__ __forceinline__ float gelu_fast(float v) {
    float u = v * v;
    float inner = v * fmaf(0.0356774081f, u, 0.7978845608f);
    float e = __builtin_amdgcn_exp2f(inner * 2.8853900818f);
    float r = __builtin_amdgcn_rcpf(e + 1.0f);
    return fmaf(-v, r, v);
}

// ---------------- k_prep: max-reduce + zero cP + build w1T(global) ----------
__global__ __launch_bounds__(256) void k_prep(const float* __restrict__ pd,
                                              const float* __restrict__ w1,
                                              float* __restrict__ invmax,
                                              float* __restrict__ cP,
                                              unsigned short* __restrict__ w1Tg) {
    int bx = blockIdx.x;
    if (bx == 0) {
        __shared__ float red[256];
        int t = threadIdx.x;
        float m = -1e30f;
        for (int i = t; i < SS; i += 256) m = fmaxf(m, pd[i]);
        red[t] = m; __syncthreads();
        for (int off = 128; off > 0; off >>= 1) {
            if (t < off) red[t] = fmaxf(red[t], red[t + off]);
            __syncthreads();
        }
        if (t == 0) invmax[0] = 1.0f / red[0];
    } else if (bx <= 1280) {
        int idx = (bx - 1) * 256 + threadIdx.x;   // 1280*256 float4 = 4*16*32*640 floats
        float4 z = {0.f, 0.f, 0.f, 0.f};
        ((float4*)cP)[idx] = z;
    } else {
        for (int idx = threadIdx.x; idx < HH * 64; idx += 256) {
            int j = idx >> 6, k = idx & 63;
            unsigned short r = 0;
            if (k < CC) r = f2bf(w1[k * HH + j]);
            else if (k >= 32 && k < 32 + CC) r = f2bflo(w1[(k - 32) * HH + j]);
            w1Tg[idx] = r;
        }
    }
}

// ---------------- shared DFT tail: LDS-staged MFMA partial DFT --------------
__device__ __forceinline__ void dft_phase(unsigned short* sh_hA, unsigned short* sh_ph,
                                          int tid, float* cPdst) {
    int wave = tid >> 6, lane = tid & 63;
    int quad = lane >> 4, frow = lane & 15;
    floatx4 acc00 = {0.f,0.f,0.f,0.f}, acc01 = {0.f,0.f,0.f,0.f};
    floatx4 acc10 = {0.f,0.f,0.f,0.f}, acc11 = {0.f,0.f,0.f,0.f};
    int kb = wave * 64 + quad * 8;
    #pragma unroll
    for (int kc = 0; kc < 2; ++kc) {
        int k = kb + kc * 32;
        short8 a0 = *(const short8*)(sh_hA + frow * RP + k);
        short8 a1 = *(const short8*)(sh_hA + (16 + frow) * RP + k);
        short8 bc = *(const short8*)(sh_ph + frow * RP + k);
        short8 bs = *(const short8*)(sh_ph + (16 + frow) * RP + k);
        acc00 = __builtin_amdgcn_mfma_f32_16x16x32_bf16(a0, bc, acc00, 0, 0, 0);
        acc01 = __builtin_amdgcn_mfma_f32_16x16x32_bf16(a0, bs, acc01, 0, 0, 0);
        acc10 = __builtin_amdgcn_mfma_f32_16x16x32_bf16(a1, bc, acc10, 0, 0, 0);
        acc11 = __builtin_amdgcn_mfma_f32_16x16x32_bf16(a1, bs, acc11, 0, 0, 0);
    }
    __syncthreads();
    float* red = (float*)sh_hA;
    #pragma unroll
    for (int r = 0; r < 4; ++r) {
        red[wave * 1024 + 0 * 256 + r * 64 + lane] = acc00[r];
        red[wave * 1024 + 1 * 256 + r * 64 + lane] = acc01[r];
        red[wave * 1024 + 2 * 256 + r * 64 + lane] = acc10[r];
        red[wave * 1024 + 3 * 256 + r * 64 + lane] = acc11[r];
    }
    __syncthreads();
    #pragma unroll
    for (int ii = 0; ii < 4; ++ii) {
        int idx = ii * 256 + tid;
        float v = red[idx] + red[1024 + idx] + red[2048 + idx] + red[3072 + idx];
        int f = idx >> 8;
        int r = (idx >> 6) & 3, ln = idx & 63;
        int o = (f >> 1) * 16 + (ln >> 4) * 4 + r;   // D row = quad*4+reg
        int m = ln & 15;                              // D col = lane&15
        if (o < CC) atomicAdd(cPdst + (f & 1) * 320 + o * 16 + m, v);
    }
}

// ---------------- k_fc0_dft: h2 (paired bf16 dwords) = fc0; DFT partials ----
// h2[p*SS+s]: lo16 = channel 2p, hi16 = channel 2p+1 — full-dword accesses
// (R13's strided ushort loads compiled to d16 pairs -> false-dep stalls).
__global__ __launch_bounds__(256, 4) void k_fc0_dft(const float* __restrict__ x,
        const float* __restrict__ pd, const float* __restrict__ w,
        const float* __restrict__ bias, const float* __restrict__ invmax,
        unsigned* __restrict__ h2, float* __restrict__ cP0) {
    __shared__ __align__(16) unsigned short sh_hA[32 * RP];
    __shared__ __align__(16) unsigned short sh_ph[32 * RP];
    int tid = threadIdx.x;
    {
        unsigned* z = (unsigned*)(sh_hA + CC * RP);
        for (int i = tid; i < (32 - CC) * RP / 2; i += 256) z[i] = 0;
    }
    int b = blockIdx.y;
    int s = blockIdx.x * 256 + tid;
    float xv = x[(size_t)b * SS + s];
    float g  = pd[s] * invmax[0];
    unsigned* hp2 = h2 + (size_t)b * (CC / 2) * SS + s;
    float u = (float)s * (1.0f / 32768.0f);
    float s1, c1; sincospif(u, &s1, &c1);
    float cm = 1.0f, sm = 0.0f;
    #pragma unroll
    for (int m = 0; m < NM; ++m) {
        sh_ph[m * RP + tid]        = f2bf(cm);
        sh_ph[(16 + m) * RP + tid] = f2bf(sm);
        float cn = cm * c1 - sm * s1;
        sm = sm * c1 + cm * s1;
        cm = cn;
    }
    #pragma unroll
    for (int p = 0; p < CC / 2; ++p) {
        int c0 = 2 * p, c1i = 2 * p + 1;
        float v0 = xv * w[c0]  + g * w[CC + c0]  + bias[c0];
        float v1 = xv * w[c1i] + g * w[CC + c1i] + bias[c1i];
        unsigned short a0 = f2bf(v0), a1 = f2bf(v1);
        hp2[(size_t)p * SS] = (unsigned)a0 | ((unsigned)a1 << 16);
        sh_hA[c0 * RP + tid]  = a0;
        sh_hA[c1i * RP + tid] = a1;
    }
    __syncthreads();
    dft_phase(sh_hA, sh_ph, tid, cP0 + ((size_t)(blockIdx.x & (NSLOT - 1)) * BB + b) * 640);
}

// ---------------- k_point_dft (layers 0..2: gelu + next-layer DFT) ----------
__global__ __launch_bounds__(256, 4) void k_point_dft(unsigned* __restrict__ h2,
        const float* __restrict__ ww, const float* __restrict__ wb,
        const float* __restrict__ cA, const float* __restrict__ cB,
        float* __restrict__ cPn) {
    __shared__ __align__(16) unsigned short sh_hA[32 * RP];
    __shared__ __align__(16) unsigned short sh_ph[32 * RP];
    int tid = threadIdx.x;
    int b = blockIdx.y;
    {
        unsigned* z = (unsigned*)(sh_hA + CC * RP);
        for (int i = tid; i < (32 - CC) * RP / 2; i += 256) z[i] = 0;
    }
    const float* wA = cA + (size_t)b * CC * NM;
    const float* wB = cB + (size_t)b * CC * NM;
    int s = blockIdx.x * 256 + tid;
    unsigned* hp2 = h2 + (size_t)b * (CC / 2) * SS + s;
    float u = (float)s * (1.0f / 32768.0f);
    float s1, c1; sincospif(u, &s1, &c1);
    float cm[NM], sm[NM];
    cm[0] = 1.0f; sm[0] = 0.0f;
    #pragma unroll
    for (int m = 1; m < NM; ++m) {
        cm[m] = cm[m - 1] * c1 - sm[m - 1] * s1;
        sm[m] = sm[m - 1] * c1 + cm[m - 1] * s1;
    }
    #pragma unroll
    for (int m = 0; m < NM; ++m) {
        sh_ph[m * RP + tid]        = f2bf(cm[m]);
        sh_ph[(16 + m) * RP + tid] = f2bf(sm[m]);
    }
    float hv[CC];
    #pragma unroll
    for (int p = 0; p < CC / 2; ++p) {
        unsigned hw = hp2[(size_t)p * SS];
        hv[2 * p]     = bf2f((unsigned short)(hw & 0xFFFFu));
        hv[2 * p + 1] = bf2f((unsigned short)(hw >> 16));
    }
    #pragma unroll 2
    for (int p = 0; p < CC / 2; ++p) {
        int o0 = 2 * p, o1 = 2 * p + 1;
        float a0 = wb[o0], a1 = wb[o1];
        #pragma unroll
        for (int c = 0; c < CC; ++c) {
            a0 += ww[o0 * CC + c] * hv[c];
            a1 += ww[o1 * CC + c] * hv[c];
        }
        #pragma unroll
        for (int m = 0; m < NM; ++m) {
            a0 += wA[o0 * NM + m] * cm[m] + wB[o0 * NM + m] * sm[m];
            a1 += wA[o1 * NM + m] * cm[m] + wB[o1 * NM + m] * sm[m];
        }
        a0 = gelu_fast(a0);
        a1 = gelu_fast(a1);
        unsigned short b0 = f2bf(a0), b1 = f2bf(a1);
        hp2[(size_t)p * SS] = (unsigned)b0 | ((unsigned)b1 << 16);
        sh_hA[o0 * RP + tid] = b0;
        sh_hA[o1 * RP + tid] = b1;
    }
    __syncthreads();
    dft_phase(sh_hA, sh_ph, tid, cPn + ((size_t)(blockIdx.x & (NSLOT - 1)) * BB + b) * 640);
}

// ---------------- k_mix: 16-slot partial reduce + complex mixing ------------
__global__ __launch_bounds__(320) void k_mix(const float* __restrict__ cP,
                                             const float* __restrict__ wre, const float* __restrict__ wim,
                                             float* __restrict__ cA, float* __restrict__ cB) {
    int b = blockIdx.x, tid = threadIdx.x;
    __shared__ float PQ[640];
    const float* base = cP + (size_t)b * 640;
    int i = tid >> 4, m = tid & 15;
    float sP = 0.f, sQ = 0.f;
    #pragma unroll 4
    for (int sl = 0; sl < NSLOT; ++sl) {
        sP += base[(size_t)sl * BB * 640 + tid];
        sQ += base[(size_t)sl * BB * 640 + 320 + tid];
    }
    PQ[i * 32 + m]      = sP;
    PQ[i * 32 + 16 + m] = sQ;
    __syncthreads();
    int o = i;
    float reY = 0.f, imY = 0.f;
    #pragma unroll
    for (int c = 0; c < CC; ++c) {
        float P = PQ[c * 32 + m], Q = PQ[c * 32 + 16 + m];
        float wr = wre[(size_t)(c * CC + o) * NM + m];
        float wi = wim[(size_t)(c * CC + o) * NM + m];
        reY += P * wr + Q * wi;                // X = P - iQ
        imY += P * wi - Q * wr;
    }
    const float invS = 1.0f / (float)SS;
    float a, bb;
    if (m == 0) { a = reY * invS; bb = 0.0f; } // irfft drops Im(DC)
    else        { a = 2.0f * reY * invS; bb = -2.0f * imY * invS; }
    cA[(size_t)(b * CC + o) * NM + m] = a;
    cB[(size_t)(b * CC + o) * NM + m] = bb;
}

// ---------------- k_point_final: layer-3 point op + fc1 MFMA + gelu + fc2 ---
// R16: LDS cut 37.9 KB -> 32.0 KB exactly (5 blocks/CU instead of 4):
//  - hT pitch 72 -> 64 (pure payload) with T2-style XOR chunk swizzle
//    (chunk ^= row&7 on 16B chunks) so writes AND b128 reads are
//    bank-conflict-free at the pow2 pitch.
//  - outS folded into hT: each wave reads only its own rows; after a tile's
//    ds_reads those rows are dead, so col==0 lanes drop the fc2 scalar into
//    the dead row (physical chunk row&7), read back after the final barrier.
__global__ __launch_bounds__(256, 4) void k_point_final(const unsigned* __restrict__ h2,
        const float* __restrict__ ww, const float* __restrict__ wb,
        const float* __restrict__ cA, const float* __restrict__ cB,
        const unsigned short* __restrict__ w1Tg, const float* __restrict__ b1,
        const float* __restrict__ w2, const float* __restrict__ b2,
        float* __restrict__ out) {
    __shared__ __align__(16) unsigned short hT[256 * WP];   // 32768 B exactly
    int tid = threadIdx.x;
    int b = blockIdx.y;
    const float* wA = cA + (size_t)b * CC * NM;
    const float* wB = cB + (size_t)b * CC * NM;

    // point op (layer 3, no gelu), pack own hT row
    int s = blockIdx.x * 256 + tid;
    const unsigned* hp2 = h2 + (size_t)b * (CC / 2) * SS + s;
    float u = (float)s * (1.0f / 32768.0f);
    float s1, c1; sincospif(u, &s1, &c1);
    float cm[NM], sm[NM];
    cm[0] = 1.0f; sm[0] = 0.0f;
    #pragma unroll
    for (int m = 1; m < NM; ++m) {
        cm[m] = cm[m - 1] * c1 - sm[m - 1] * s1;
        sm[m] = sm[m - 1] * c1 + cm[m - 1] * s1;
    }
    float hv[CC];
    #pragma unroll
    for (int p = 0; p < CC / 2; ++p) {
        unsigned hw = hp2[(size_t)p * SS];
        hv[2 * p]     = bf2f((unsigned short)(hw & 0xFFFFu));
        hv[2 * p + 1] = bf2f((unsigned short)(hw >> 16));
    }
    short8 rowf[8];
    #pragma unroll
    for (int ch = 0; ch < 8; ++ch) rowf[ch] = (short8){0,0,0,0,0,0,0,0};
    #pragma unroll        // FULL unroll required (R5 scratch lesson)
    for (int o = 0; o < CC; ++o) {
        float a = wb[o];
        #pragma unroll
        for (int c = 0; c < CC; ++c) a += ww[o * CC + c] * hv[c];
        #pragma unroll
        for (int m = 0; m < NM; ++m)
            a += wA[o * NM + m] * cm[m] + wB[o * NM + m] * sm[m];
        unsigned short hi = f2bf(a);
        rowf[o >> 3][o & 7]       = (short)hi;
        rowf[4 + (o >> 3)][o & 7] = (short)f2bf(a - bf2f(hi));
    }
    #pragma unroll
    for (int ch = 0; ch < 8; ++ch)
        *(short8*)(hT + tid * WP + ((ch ^ (tid & 7)) << 3)) = rowf[ch];
    __syncthreads();

    // fc1 B-fragments from global (L2-resident) — after the point-op (R8)
    int wave = tid >> 6, lane = tid & 63;
    int col = lane & 15, quad = lane >> 4;
    short8 bhi[8], blo[8];
    #pragma unroll
    for (int nt = 0; nt < 8; ++nt) {
        bhi[nt] = *(const short8*)(w1Tg + (size_t)(nt * 16 + col) * 64 + quad * 8);
        blo[nt] = *(const short8*)(w1Tg + (size_t)(nt * 16 + col) * 64 + 32 + quad * 8);
    }
    float lb1r[8], w2r[8];
    #pragma unroll
    for (int nt = 0; nt < 8; ++nt) { lb1r[nt] = b1[nt * 16 + col]; w2r[nt] = w2[nt * 16 + col]; }
    float b2v = b2[0];
    #pragma unroll
    for (int mt = 0; mt < 4; ++mt) {
        int srow = wave * 64 + mt * 16 + col;     // A row m = lane&15
        int sw = srow & 7;
        short8 ahi = *(const short8*)(hT + srow * WP + ((quad ^ sw) << 3));
        short8 alo = *(const short8*)(hT + srow * WP + (((quad ^ sw) ^ 4) << 3));
        float part[4] = {0.f, 0.f, 0.f, 0.f};
        #pragma unroll
        for (int nt = 0; nt < 8; ++nt) {
            floatx4 a = {0.f, 0.f, 0.f, 0.f};
            a = __builtin_amdgcn_mfma_f32_16x16x32_bf16(ahi, bhi[nt], a, 0, 0, 0);
            a = __builtin_amdgcn_mfma_f32_16x16x32_bf16(ahi, blo[nt], a, 0, 0, 0);
            a = __builtin_amdgcn_mfma_f32_16x16x32_bf16(alo, bhi[nt], a, 0, 0, 0);
            #pragma unroll
            for (int r = 0; r < 4; ++r) {
                float t = gelu_fast(a[r] + lb1r[nt]);
                part[r] += t * w2r[nt];
            }
        }
        #pragma unroll
        for (int r = 0; r < 4; ++r) {
            float p = part[r];
            p += __shfl_xor(p, 1, 64);
            p += __shfl_xor(p, 2, 64);
            p += __shfl_xor(p, 4, 64);
            p += __shfl_xor(p, 8, 64);
            if (col == 0) {
                int row = wave * 64 + mt * 16 + quad * 4 + r;   // rows of this tile: dead in hT
                *(float*)(&hT[row * WP + ((row & 7) << 3)]) = p + b2v;
            }
        }
    }
    __syncthreads();
    out[(size_t)b * SS + blockIdx.x * 256 + tid] = *(const float*)(&hT[tid * WP + ((tid & 7) << 3)]);
}

extern "C" void kernel_launch(void* const* d_in, const int* in_sizes, int n_in,
                              void* d_out, int out_size, void* d_ws, size_t ws_size,
                              hipStream_t stream) {
    (void)in_sizes; (void)n_in; (void)out_size; (void)ws_size;
    const float* x    = (const float*)d_in[0];
    const float* pd   = (const float*)d_in[1];
    const float* fc0w = (const float*)d_in[2];
    const float* fc0b = (const float*)d_in[3];
    const float* fc1w = (const float*)d_in[4];
    const float* fc1b = (const float*)d_in[5];
    const float* fc2w = (const float*)d_in[6];
    const float* fc2b = (const float*)d_in[7];

    char* ws = (char*)d_ws;
    unsigned* h2 = (unsigned*)ws;
    size_t off = (size_t)BB * (CC / 2) * SS * 4;                      // 83.9 MB (paired bf16)
    float* cP = (float*)(ws + off); off += (size_t)4 * NSLOT * BB * 640 * 4;  // 5.24 MB
    float* cA = (float*)(ws + off); off += (size_t)BB * CC * NM * 4;
    float* cB = (float*)(ws + off); off += (size_t)BB * CC * NM * 4;
    float* invmax = (float*)(ws + off); off += 256;
    unsigned short* w1Tg = (unsigned short*)(ws + off); off += (size_t)HH * 64 * 2;  // 16 KB
    const size_t CPL = (size_t)NSLOT * BB * 640;   // floats per layer-slot set

    dim3 gBS(SS / 256, BB);

    k_prep<<<1282, 256, 0, stream>>>(pd, fc1w, invmax, cP, w1Tg);
    k_fc0_dft<<<gBS, 256, 0, stream>>>(x, pd, fc0w, fc0b, invmax, h2, cP);

    for (int l = 0; l < 3; ++l) {
        const float* wre = (const float*)d_in[8 + 4 * l];
        const float* wim = (const float*)d_in[9 + 4 * l];
        const float* ww  = (const float*)d_in[10 + 4 * l];
        const float* wb  = (const float*)d_in[11 + 4 * l];
        k_mix<<<BB, 320, 0, stream>>>(cP + (size_t)l * CPL, wre, wim, cA, cB);
        k_point_dft<<<gBS, 256, 0, stream>>>(h2, ww, wb, cA, cB,
                                             cP + (size_t)(l + 1) * CPL);
    }
    {   // layer 3 fused with fc1/gelu/fc2
        const float* wre = (const float*)d_in[20];
        const float* wim = (const float*)d_in[21];
        const float* ww  = (const float*)d_in[22];
        const float* wb  = (const float*)d_in[23];
        k_mix<<<BB, 320, 0, stream>>>(cP + (size_t)3 * CPL, wre, wim, cA, cB);
        k_point_final<<<gBS, 256, 0, stream>>>(h2, ww, wb, cA, cB,
                                               w1Tg, fc1b, fc2w, fc2b, (float*)d_out);
    }
}

// Round 3
// 653.902 us; speedup vs baseline: 1.0682x; 1.0682x over previous
//
#include <hip/hip_runtime.h>
#include <math.h>

#define BB 32
#define SS 65536
#define CC 20
#define NM 16
#define HH 128
#define RP 264   // DFT LDS row pitch (bf16 elems)
#define WP 64    // hT row pitch (bf16 elems): 8x short8 payload, XOR-swizzled chunks
#define NSLOT 16

using short8  = __attribute__((ext_vector_type(8))) short;
using floatx4 = __attribute__((ext_vector_type(4))) float;

__device__ __forceinline__ unsigned short f2bf(float f) {
    union { float f; unsigned u; } v; v.f = f;
    unsigned u = v.u;
    return (unsigned short)((u + 0x7FFFu + ((u >> 16) & 1u)) >> 16);   // RNE
}
__device__ __forceinline__ float bf2f(unsigned short h) {
    union { unsigned u; float f; } v; v.u = ((unsigned)h) << 16; return v.f;
}
__device__ __forceinline__ unsigned short f2bflo(float a) {
    return f2bf(a - bf2f(f2bf(a)));
}
__device__ __forceinline__ unsigned pk2(unsigned short lo, unsigned short hi) {
    return (unsigned)lo | ((unsigned)hi << 16);
}

// Tanh-form gelu, native exp2/rcp (R11). |delta| vs erf-gelu ~3e-4.
// NOTE (R15 lesson): keep all WEIGHT reads as scalar float loads — vector-
// typed (float2/float4) loads from uniform addresses defeat s_load
// scalarization and regress 2.3x.
__device__ __forceinline__ float gelu_fast(float v) {
    float u = v * v;
    float inner = v * fmaf(0.0356774081f, u, 0.7978845608f);
    float e = __builtin_amdgcn_exp2f(inner * 2.8853900818f);
    float r = __builtin_amdgcn_rcpf(e + 1.0f);
    return fmaf(-v, r, v);
}

// ---------------- k_prep: max-reduce + zero cP + build w1T(global) ----------
__global__ __launch_bounds__(256) void k_prep(const float* __restrict__ pd,
                                              const float* __restrict__ w1,
                                              float* __restrict__ invmax,
                                              float* __restrict__ cP,
                                              unsigned short* __restrict__ w1Tg) {
    int bx = blockIdx.x;
    if (bx == 0) {
        __shared__ float red[256];
        int t = threadIdx.x;
        float m = -1e30f;
        for (int i = t; i < SS; i += 256) m = fmaxf(m, pd[i]);
        red[t] = m; __syncthreads();
        for (int off = 128; off > 0; off >>= 1) {
            if (t < off) red[t] = fmaxf(red[t], red[t + off]);
            __syncthreads();
        }
        if (t == 0) invmax[0] = 1.0f / red[0];
    } else if (bx <= 1280) {
        int idx = (bx - 1) * 256 + threadIdx.x;   // 1280*256 float4 = 4*16*32*640 floats
        float4 z = {0.f, 0.f, 0.f, 0.f};
        ((float4*)cP)[idx] = z;
    } else {
        for (int idx = threadIdx.x; idx < HH * 64; idx += 256) {
            int j = idx >> 6, k = idx & 63;
            unsigned short r = 0;
            if (k < CC) r = f2bf(w1[k * HH + j]);
            else if (k >= 32 && k < 32 + CC) r = f2bflo(w1[(k - 32) * HH + j]);
            w1Tg[idx] = r;
        }
    }
}

// ---------------- shared DFT tail: LDS-staged MFMA partial DFT --------------
__device__ __forceinline__ void dft_phase(unsigned short* sh_hA, unsigned short* sh_ph,
                                          int tid, float* cPdst) {
    int wave = tid >> 6, lane = tid & 63;
    int quad = lane >> 4, frow = lane & 15;
    floatx4 acc00 = {0.f,0.f,0.f,0.f}, acc01 = {0.f,0.f,0.f,0.f};
    floatx4 acc10 = {0.f,0.f,0.f,0.f}, acc11 = {0.f,0.f,0.f,0.f};
    int kb = wave * 64 + quad * 8;
    #pragma unroll
    for (int kc = 0; kc < 2; ++kc) {
        int k = kb + kc * 32;
        short8 a0 = *(const short8*)(sh_hA + frow * RP + k);
        short8 a1 = *(const short8*)(sh_hA + (16 + frow) * RP + k);
        short8 bc = *(const short8*)(sh_ph + frow * RP + k);
        short8 bs = *(const short8*)(sh_ph + (16 + frow) * RP + k);
        acc00 = __builtin_amdgcn_mfma_f32_16x16x32_bf16(a0, bc, acc00, 0, 0, 0);
        acc01 = __builtin_amdgcn_mfma_f32_16x16x32_bf16(a0, bs, acc01, 0, 0, 0);
        acc10 = __builtin_amdgcn_mfma_f32_16x16x32_bf16(a1, bc, acc10, 0, 0, 0);
        acc11 = __builtin_amdgcn_mfma_f32_16x16x32_bf16(a1, bs, acc11, 0, 0, 0);
    }
    __syncthreads();
    float* red = (float*)sh_hA;
    #pragma unroll
    for (int r = 0; r < 4; ++r) {
        red[wave * 1024 + 0 * 256 + r * 64 + lane] = acc00[r];
        red[wave * 1024 + 1 * 256 + r * 64 + lane] = acc01[r];
        red[wave * 1024 + 2 * 256 + r * 64 + lane] = acc10[r];
        red[wave * 1024 + 3 * 256 + r * 64 + lane] = acc11[r];
    }
    __syncthreads();
    #pragma unroll
    for (int ii = 0; ii < 4; ++ii) {
        int idx = ii * 256 + tid;
        float v = red[idx] + red[1024 + idx] + red[2048 + idx] + red[3072 + idx];
        int f = idx >> 8;
        int r = (idx >> 6) & 3, ln = idx & 63;
        int o = (f >> 1) * 16 + (ln >> 4) * 4 + r;   // D row = quad*4+reg
        int m = ln & 15;                              // D col = lane&15
        if (o < CC) atomicAdd(cPdst + (f & 1) * 320 + o * 16 + m, v);
    }
}

// ---------------- k_fc0_dft: h2 (paired bf16 dwords) = fc0; DFT partials ----
__global__ __launch_bounds__(256, 4) void k_fc0_dft(const float* __restrict__ x,
        const float* __restrict__ pd, const float* __restrict__ w,
        const float* __restrict__ bias, const float* __restrict__ invmax,
        unsigned* __restrict__ h2, float* __restrict__ cP0) {
    __shared__ __align__(16) unsigned short sh_hA[32 * RP];
    __shared__ __align__(16) unsigned short sh_ph[32 * RP];
    int tid = threadIdx.x;
    {
        unsigned* z = (unsigned*)(sh_hA + CC * RP);
        for (int i = tid; i < (32 - CC) * RP / 2; i += 256) z[i] = 0;
    }
    int b = blockIdx.y;
    int s = blockIdx.x * 256 + tid;
    float xv = x[(size_t)b * SS + s];
    float g  = pd[s] * invmax[0];
    unsigned* hp2 = h2 + (size_t)b * (CC / 2) * SS + s;
    float u = (float)s * (1.0f / 32768.0f);
    float s1, c1; sincospif(u, &s1, &c1);
    float cm = 1.0f, sm = 0.0f;
    #pragma unroll
    for (int m = 0; m < NM; ++m) {
        sh_ph[m * RP + tid]        = f2bf(cm);
        sh_ph[(16 + m) * RP + tid] = f2bf(sm);
        float cn = cm * c1 - sm * s1;
        sm = sm * c1 + cm * s1;
        cm = cn;
    }
    #pragma unroll
    for (int p = 0; p < CC / 2; ++p) {
        int c0 = 2 * p, c1i = 2 * p + 1;
        float v0 = xv * w[c0]  + g * w[CC + c0]  + bias[c0];
        float v1 = xv * w[c1i] + g * w[CC + c1i] + bias[c1i];
        unsigned short a0 = f2bf(v0), a1 = f2bf(v1);
        hp2[(size_t)p * SS] = (unsigned)a0 | ((unsigned)a1 << 16);
        sh_hA[c0 * RP + tid]  = a0;
        sh_hA[c1i * RP + tid] = a1;
    }
    __syncthreads();
    dft_phase(sh_hA, sh_ph, tid, cP0 + ((size_t)(blockIdx.x & (NSLOT - 1)) * BB + b) * 640);
}

// ---------------- k_point_dft (layers 0..2): MFMA point-op + next-layer DFT -
// R17: the 20x(20ch+32spectral) per-thread FMA loop (1040 VALU FMA) is now a
// 256x20 GEMM with K=64: A[s] = [h(20) | 1 | pad | cm_hi(16) | sm_hi(16)],
// A_lo[s] = [cm_lo | sm_lo] (K=32), B panels (ww/bias/cA/cB hi+lo bf16)
// pre-packed per-batch by k_mix. 5 MFMA per 16x16 tile:
//   ahi0*bhi0 + ahi1*bhi1 + ahi0*blo0 + ahi1*blo1 + alo*bhi1
// (only the ~1e-6 trig_lo*w_lo term is dropped -> f32-grade accuracy).
// A staged in 48KB LDS (XOR chunk swizzle, same pattern as hT in R16);
// sh_hA/sh_ph union the A-stage behind a barrier. 3 blocks/CU.
__global__ __launch_bounds__(256, 3) void k_point_dft(unsigned* __restrict__ h2,
        const unsigned short* __restrict__ Bpk,
        float* __restrict__ cPn) {
    __shared__ __align__(16) unsigned short AST[256 * 64 + 256 * 32];   // 48 KB
    unsigned short* ALO   = AST + 256 * 64;
    unsigned short* sh_hA = AST;                 // aliases, valid after barrier
    unsigned short* sh_ph = AST + 32 * RP;
    int tid = threadIdx.x;
    int b = blockIdx.y;
    int s = blockIdx.x * 256 + tid;

    // ---- phase A: trig + old-h load + A-row staging -------------------
    float u = (float)s * (1.0f / 32768.0f);
    float s1, c1; sincospif(u, &s1, &c1);
    float cm[NM], sm[NM];
    cm[0] = 1.0f; sm[0] = 0.0f;
    #pragma unroll
    for (int m = 1; m < NM; ++m) {
        cm[m] = cm[m - 1] * c1 - sm[m - 1] * s1;
        sm[m] = sm[m - 1] * c1 + cm[m - 1] * s1;
    }
    const unsigned* hp2r = h2 + (size_t)b * (CC / 2) * SS + s;
    unsigned hw[CC / 2];
    #pragma unroll
    for (int p = 0; p < CC / 2; ++p) hw[p] = hp2r[(size_t)p * SS];

    unsigned short chi[NM], shi[NM], clo[NM], slo[NM];
    #pragma unroll
    for (int m = 0; m < NM; ++m) {
        chi[m] = f2bf(cm[m]);  clo[m] = f2bf(cm[m] - bf2f(chi[m]));
        shi[m] = f2bf(sm[m]);  slo[m] = f2bf(sm[m] - bf2f(shi[m]));
    }
    {   // hi row: 8 swizzled 16B chunks
        uint4 q;
        int sw = tid & 7;
        unsigned* base = (unsigned*)(AST + tid * 64);
        q = (uint4){hw[0], hw[1], hw[2], hw[3]};
        *(uint4*)(base + ((0 ^ sw) << 2)) = q;
        q = (uint4){hw[4], hw[5], hw[6], hw[7]};
        *(uint4*)(base + ((1 ^ sw) << 2)) = q;
        q = (uint4){hw[8], hw[9], 0x00003F80u, 0u};        // elems 16..23: h16..19, ONE(bias), 0
        *(uint4*)(base + ((2 ^ sw) << 2)) = q;
        q = (uint4){0u, 0u, 0u, 0u};
        *(uint4*)(base + ((3 ^ sw) << 2)) = q;
        q = (uint4){pk2(chi[0],chi[1]), pk2(chi[2],chi[3]), pk2(chi[4],chi[5]), pk2(chi[6],chi[7])};
        *(uint4*)(base + ((4 ^ sw) << 2)) = q;
        q = (uint4){pk2(chi[8],chi[9]), pk2(chi[10],chi[11]), pk2(chi[12],chi[13]), pk2(chi[14],chi[15])};
        *(uint4*)(base + ((5 ^ sw) << 2)) = q;
        q = (uint4){pk2(shi[0],shi[1]), pk2(shi[2],shi[3]), pk2(shi[4],shi[5]), pk2(shi[6],shi[7])};
        *(uint4*)(base + ((6 ^ sw) << 2)) = q;
        q = (uint4){pk2(shi[8],shi[9]), pk2(shi[10],shi[11]), pk2(shi[12],shi[13]), pk2(shi[14],shi[15])};
        *(uint4*)(base + ((7 ^ sw) << 2)) = q;
        // lo row: 4 swizzled chunks [cm_lo(16) | sm_lo(16)]
        int sw3 = tid & 3;
        unsigned* lbase = (unsigned*)(ALO + tid * 32);
        q = (uint4){pk2(clo[0],clo[1]), pk2(clo[2],clo[3]), pk2(clo[4],clo[5]), pk2(clo[6],clo[7])};
        *(uint4*)(lbase + ((0 ^ sw3) << 2)) = q;
        q = (uint4){pk2(clo[8],clo[9]), pk2(clo[10],clo[11]), pk2(clo[12],clo[13]), pk2(clo[14],clo[15])};
        *(uint4*)(lbase + ((1 ^ sw3) << 2)) = q;
        q = (uint4){pk2(slo[0],slo[1]), pk2(slo[2],slo[3]), pk2(slo[4],slo[5]), pk2(slo[6],slo[7])};
        *(uint4*)(lbase + ((2 ^ sw3) << 2)) = q;
        q = (uint4){pk2(slo[8],slo[9]), pk2(slo[10],slo[11]), pk2(slo[12],slo[13]), pk2(slo[14],slo[15])};
        *(uint4*)(lbase + ((3 ^ sw3) << 2)) = q;
    }
    __syncthreads();

    // ---- phase B: MFMA point-op, gelu, pack ---------------------------
    int wave = tid >> 6, lane = tid & 63, col = lane & 15, quad = lane >> 4;
    const unsigned short* Bp = Bpk + (size_t)b * 4096;
    short8 bh0[2], bh1[2], bl0[2], bl1[2];
    #pragma unroll
    for (int nt = 0; nt < 2; ++nt) {
        int o = nt * 16 + col;
        bh0[nt] = *(const short8*)(Bp + o * 64 + quad * 8);
        bh1[nt] = *(const short8*)(Bp + o * 64 + 32 + quad * 8);
        bl0[nt] = *(const short8*)(Bp + 2048 + o * 64 + quad * 8);
        bl1[nt] = *(const short8*)(Bp + 2048 + o * 64 + 32 + quad * 8);
    }
    unsigned packres[2][8];
    #pragma unroll
    for (int mt = 0; mt < 4; ++mt) {
        int ar = wave * 64 + mt * 16 + col;
        int sw = ar & 7;
        const unsigned short* abase = AST + ar * 64;
        short8 ah0 = *(const short8*)(abase + ((quad ^ sw) << 3));
        short8 ah1 = *(const short8*)(abase + (((4 + quad) ^ sw) << 3));
        short8 al  = *(const short8*)(ALO + ar * 32 + ((quad ^ (ar & 3)) << 3));
        #pragma unroll
        for (int nt = 0; nt < 2; ++nt) {
            floatx4 a = {0.f, 0.f, 0.f, 0.f};
            a = __builtin_amdgcn_mfma_f32_16x16x32_bf16(ah0, bh0[nt], a, 0, 0, 0);
            a = __builtin_amdgcn_mfma_f32_16x16x32_bf16(ah1, bh1[nt], a, 0, 0, 0);
            a = __builtin_amdgcn_mfma_f32_16x16x32_bf16(ah0, bl0[nt], a, 0, 0, 0);
            a = __builtin_amdgcn_mfma_f32_16x16x32_bf16(ah1, bl1[nt], a, 0, 0, 0);
            a = __builtin_amdgcn_mfma_f32_16x16x32_bf16(al,  bh1[nt], a, 0, 0, 0);
            unsigned short r0 = f2bf(gelu_fast(a[0]));
            unsigned short r1 = f2bf(gelu_fast(a[1]));
            unsigned short r2 = f2bf(gelu_fast(a[2]));
            unsigned short r3 = f2bf(gelu_fast(a[3]));
            packres[nt][mt * 2 + 0] = pk2(r0, r1);
            packres[nt][mt * 2 + 1] = pk2(r2, r3);
        }
    }
    __syncthreads();   // all A-stage reads done; LDS now re-used as sh_hA/sh_ph

    // ---- phase C: scatter h_new to sh_hA, write sh_ph, store h2 -------
    {
        unsigned* z = (unsigned*)(sh_hA + CC * RP);
        #pragma unroll
        for (int i = tid; i < (32 - CC) * RP / 2; i += 256) z[i] = 0;
    }
    #pragma unroll
    for (int m = 0; m < NM; ++m) {
        sh_ph[m * RP + tid]        = f2bf(cm[m]);
        sh_ph[(16 + m) * RP + tid] = f2bf(sm[m]);
    }
    unsigned* h2b = h2 + (size_t)b * (CC / 2) * SS + blockIdx.x * 256;
    #pragma unroll
    for (int nt = 0; nt < 2; ++nt) {
        int o = nt * 16 + col;
        bool valid = (o < CC);
        #pragma unroll
        for (int mt = 0; mt < 4; ++mt) {
            int sb = wave * 64 + mt * 16 + quad * 4;
            #pragma unroll
            for (int rp = 0; rp < 2; ++rp) {
                unsigned dw = packres[nt][mt * 2 + rp];
                if (valid) {
                    sh_hA[o * RP + sb + 2 * rp]     = (unsigned short)(dw & 0xFFFFu);
                    sh_hA[o * RP + sb + 2 * rp + 1] = (unsigned short)(dw >> 16);
                }
                unsigned pdw = __shfl_xor(dw, 1, 64);
                if (valid && !(col & 1)) {
                    int p = o >> 1;
                    h2b[(size_t)p * SS + sb + 2 * rp]     = (dw & 0xFFFFu) | (pdw << 16);
                    h2b[(size_t)p * SS + sb + 2 * rp + 1] = (dw >> 16) | (pdw & 0xFFFF0000u);
                }
            }
        }
    }
    __syncthreads();
    dft_phase(sh_hA, sh_ph, tid, cPn + ((size_t)(blockIdx.x & (NSLOT - 1)) * BB + b) * 640);
}

// ---------------- k_mix: partial reduce + complex mixing + B-panel pack -----
__global__ __launch_bounds__(320) void k_mix(const float* __restrict__ cP,
                                             const float* __restrict__ wre, const float* __restrict__ wim,
                                             const float* __restrict__ ww, const float* __restrict__ wb,
                                             float* __restrict__ cA, float* __restrict__ cB,
                                             unsigned short* __restrict__ Bpk) {
    int b = blockIdx.x, tid = threadIdx.x;
    __shared__ float PQ[640];
    const float* base = cP + (size_t)b * 640;
    int i = tid >> 4, m = tid & 15;
    float sP = 0.f, sQ = 0.f;
    #pragma unroll 4
    for (int sl = 0; sl < NSLOT; ++sl) {
        sP += base[(size_t)sl * BB * 640 + tid];
        sQ += base[(size_t)sl * BB * 640 + 320 + tid];
    }
    PQ[i * 32 + m]      = sP;
    PQ[i * 32 + 16 + m] = sQ;
    __syncthreads();
    int o = i;
    float reY = 0.f, imY = 0.f;
    #pragma unroll
    for (int c = 0; c < CC; ++c) {
        float P = PQ[c * 32 + m], Q = PQ[c * 32 + 16 + m];
        float wr = wre[(size_t)(c * CC + o) * NM + m];
        float wi = wim[(size_t)(c * CC + o) * NM + m];
        reY += P * wr + Q * wi;                // X = P - iQ
        imY += P * wi - Q * wr;
    }
    const float invS = 1.0f / (float)SS;
    float a, bb;
    if (m == 0) { a = reY * invS; bb = 0.0f; } // irfft drops Im(DC)
    else        { a = 2.0f * reY * invS; bb = -2.0f * imY * invS; }
    cA[(size_t)(b * CC + o) * NM + m] = a;
    cB[(size_t)(b * CC + o) * NM + m] = bb;

    // ---- pack B panels for k_point_dft's MFMA point-op (per-b) -------
    // Bh[o][k64]: k<20 ww_hi, k==20 wb_hi, 21..31 zero, 32..47 cA_hi, 48..63 cB_hi
    // Bl: same with lo parts. Disjoint writer sets -> no extra barrier.
    unsigned short* Bp = Bpk + (size_t)b * 4096;
    for (int idx = tid; idx < 640; idx += 320) {       // o<20, k 0..31
        int o8 = idx >> 5, k = idx & 31;
        float v = 0.f;
        if (k < CC) v = ww[o8 * CC + k];
        else if (k == CC) v = wb[o8];
        Bp[o8 * 64 + k]        = f2bf(v);
        Bp[2048 + o8 * 64 + k] = f2bflo(v);
    }
    for (int idx = tid; idx < 768; idx += 320) {       // o 20..31: zero rows
        int o8 = 20 + (idx >> 6), k = idx & 63;
        Bp[o8 * 64 + k] = 0;
        Bp[2048 + o8 * 64 + k] = 0;
    }
    Bp[o * 64 + 32 + m]        = f2bf(a);
    Bp[o * 64 + 48 + m]        = f2bf(bb);
    Bp[2048 + o * 64 + 32 + m] = f2bflo(a);
    Bp[2048 + o * 64 + 48 + m] = f2bflo(bb);
}

// ---------------- k_point_final: layer-3 point op + fc1 MFMA + gelu + fc2 ---
__global__ __launch_bounds__(256, 4) void k_point_final(const unsigned* __restrict__ h2,
        const float* __restrict__ ww, const float* __restrict__ wb,
        const float* __restrict__ cA, const float* __restrict__ cB,
        const unsigned short* __restrict__ w1Tg, const float* __restrict__ b1,
        const float* __restrict__ w2, const float* __restrict__ b2,
        float* __restrict__ out) {
    __shared__ __align__(16) unsigned short hT[256 * WP];   // 32768 B exactly
    int tid = threadIdx.x;
    int b = blockIdx.y;
    const float* wA = cA + (size_t)b * CC * NM;
    const float* wB = cB + (size_t)b * CC * NM;

    int s = blockIdx.x * 256 + tid;
    const unsigned* hp2 = h2 + (size_t)b * (CC / 2) * SS + s;
    float u = (float)s * (1.0f / 32768.0f);
    float s1, c1; sincospif(u, &s1, &c1);
    float cm[NM], sm[NM];
    cm[0] = 1.0f; sm[0] = 0.0f;
    #pragma unroll
    for (int m = 1; m < NM; ++m) {
        cm[m] = cm[m - 1] * c1 - sm[m - 1] * s1;
        sm[m] = sm[m - 1] * c1 + cm[m - 1] * s1;
    }
    float hv[CC];
    #pragma unroll
    for (int p = 0; p < CC / 2; ++p) {
        unsigned hw = hp2[(size_t)p * SS];
        hv[2 * p]     = bf2f((unsigned short)(hw & 0xFFFFu));
        hv[2 * p + 1] = bf2f((unsigned short)(hw >> 16));
    }
    short8 rowf[8];
    #pragma unroll
    for (int ch = 0; ch < 8; ++ch) rowf[ch] = (short8){0,0,0,0,0,0,0,0};
    #pragma unroll        // FULL unroll required (R5 scratch lesson)
    for (int o = 0; o < CC; ++o) {
        float a = wb[o];
        #pragma unroll
        for (int c = 0; c < CC; ++c) a += ww[o * CC + c] * hv[c];
        #pragma unroll
        for (int m = 0; m < NM; ++m)
            a += wA[o * NM + m] * cm[m] + wB[o * NM + m] * sm[m];
        unsigned short hi = f2bf(a);
        rowf[o >> 3][o & 7]       = (short)hi;
        rowf[4 + (o >> 3)][o & 7] = (short)f2bf(a - bf2f(hi));
    }
    #pragma unroll
    for (int ch = 0; ch < 8; ++ch)
        *(short8*)(hT + tid * WP + ((ch ^ (tid & 7)) << 3)) = rowf[ch];
    __syncthreads();

    int wave = tid >> 6, lane = tid & 63;
    int col = lane & 15, quad = lane >> 4;
    short8 bhi[8], blo[8];
    #pragma unroll
    for (int nt = 0; nt < 8; ++nt) {
        bhi[nt] = *(const short8*)(w1Tg + (size_t)(nt * 16 + col) * 64 + quad * 8);
        blo[nt] = *(const short8*)(w1Tg + (size_t)(nt * 16 + col) * 64 + 32 + quad * 8);
    }
    float lb1r[8], w2r[8];
    #pragma unroll
    for (int nt = 0; nt < 8; ++nt) { lb1r[nt] = b1[nt * 16 + col]; w2r[nt] = w2[nt * 16 + col]; }
    float b2v = b2[0];
    #pragma unroll
    for (int mt = 0; mt < 4; ++mt) {
        int srow = wave * 64 + mt * 16 + col;     // A row m = lane&15
        int sw = srow & 7;
        short8 ahi = *(const short8*)(hT + srow * WP + ((quad ^ sw) << 3));
        short8 alo = *(const short8*)(hT + srow * WP + (((quad ^ sw) ^ 4) << 3));
        float part[4] = {0.f, 0.f, 0.f, 0.f};
        #pragma unroll
        for (int nt = 0; nt < 8; ++nt) {
            floatx4 a = {0.f, 0.f, 0.f, 0.f};
            a = __builtin_amdgcn_mfma_f32_16x16x32_bf16(ahi, bhi[nt], a, 0, 0, 0);
            a = __builtin_amdgcn_mfma_f32_16x16x32_bf16(ahi, blo[nt], a, 0, 0, 0);
            a = __builtin_amdgcn_mfma_f32_16x16x32_bf16(alo, bhi[nt], a, 0, 0, 0);
            #pragma unroll
            for (int r = 0; r < 4; ++r) {
                float t = gelu_fast(a[r] + lb1r[nt]);
                part[r] += t * w2r[nt];
            }
        }
        #pragma unroll
        for (int r = 0; r < 4; ++r) {
            float p = part[r];
            p += __shfl_xor(p, 1, 64);
            p += __shfl_xor(p, 2, 64);
            p += __shfl_xor(p, 4, 64);
            p += __shfl_xor(p, 8, 64);
            if (col == 0) {
                int row = wave * 64 + mt * 16 + quad * 4 + r;   // rows of this tile: dead in hT
                *(float*)(&hT[row * WP + ((row & 7) << 3)]) = p + b2v;
            }
        }
    }
    __syncthreads();
    out[(size_t)b * SS + blockIdx.x * 256 + tid] = *(const float*)(&hT[tid * WP + ((tid & 7) << 3)]);
}

extern "C" void kernel_launch(void* const* d_in, const int* in_sizes, int n_in,
                              void* d_out, int out_size, void* d_ws, size_t ws_size,
                              hipStream_t stream) {
    (void)in_sizes; (void)n_in; (void)out_size; (void)ws_size;
    const float* x    = (const float*)d_in[0];
    const float* pd   = (const float*)d_in[1];
    const float* fc0w = (const float*)d_in[2];
    const float* fc0b = (const float*)d_in[3];
    const float* fc1w = (const float*)d_in[4];
    const float* fc1b = (const float*)d_in[5];
    const float* fc2w = (const float*)d_in[6];
    const float* fc2b = (const float*)d_in[7];

    char* ws = (char*)d_ws;
    unsigned* h2 = (unsigned*)ws;
    size_t off = (size_t)BB * (CC / 2) * SS * 4;                      // 83.9 MB (paired bf16)
    float* cP = (float*)(ws + off); off += (size_t)4 * NSLOT * BB * 640 * 4;  // 5.24 MB
    float* cA = (float*)(ws + off); off += (size_t)BB * CC * NM * 4;
    float* cB = (float*)(ws + off); off += (size_t)BB * CC * NM * 4;
    float* invmax = (float*)(ws + off); off += 256;
    unsigned short* w1Tg = (unsigned short*)(ws + off); off += (size_t)HH * 64 * 2;  // 16 KB
    unsigned short* Bpk  = (unsigned short*)(ws + off); off += (size_t)BB * 4096 * 2; // 256 KB
    const size_t CPL = (size_t)NSLOT * BB * 640;   // floats per layer-slot set

    dim3 gBS(SS / 256, BB);

    k_prep<<<1282, 256, 0, stream>>>(pd, fc1w, invmax, cP, w1Tg);
    k_fc0_dft<<<gBS, 256, 0, stream>>>(x, pd, fc0w, fc0b, invmax, h2, cP);

    for (int l = 0; l < 3; ++l) {
        const float* wre = (const float*)d_in[8 + 4 * l];
        const float* wim = (const float*)d_in[9 + 4 * l];
        const float* ww  = (const float*)d_in[10 + 4 * l];
        const float* wb  = (const float*)d_in[11 + 4 * l];
        k_mix<<<BB, 320, 0, stream>>>(cP + (size_t)l * CPL, wre, wim, ww, wb, cA, cB, Bpk);
        k_point_dft<<<gBS, 256, 0, stream>>>(h2, Bpk, cP + (size_t)(l + 1) * CPL);
    }
    {   // layer 3 fused with fc1/gelu/fc2
        const float* wre = (const float*)d_in[20];
        const float* wim = (const float*)d_in[21];
        const float* ww  = (const float*)d_in[22];
        const float* wb  = (const float*)d_in[23];
        k_mix<<<BB, 320, 0, stream>>>(cP + (size_t)3 * CPL, wre, wim, ww, wb, cA, cB, Bpk);
        k_point_final<<<gBS, 256, 0, stream>>>(h2, ww, wb, cA, cB,
                                               w1Tg, fc1b, fc2w, fc2b, (float*)d_out);
    }
}

// Round 4
// 648.346 us; speedup vs baseline: 1.0774x; 1.0086x over previous
//
#include <hip/hip_runtime.h>
#include <math.h>

#define BB 32
#define SS 65536
#define CC 20
#define NM 16
#define HH 128
#define RP 264   // DFT LDS row pitch (bf16 elems)
#define WP 64    // hT row pitch (bf16 elems): 8x short8 payload, XOR-swizzled chunks
#define NSLOT 16

using short8  = __attribute__((ext_vector_type(8))) short;
using floatx4 = __attribute__((ext_vector_type(4))) float;

__device__ __forceinline__ unsigned short f2bf(float f) {
    union { float f; unsigned u; } v; v.f = f;
    unsigned u = v.u;
    return (unsigned short)((u + 0x7FFFu + ((u >> 16) & 1u)) >> 16);   // RNE
}
__device__ __forceinline__ float bf2f(unsigned short h) {
    union { unsigned u; float f; } v; v.u = ((unsigned)h) << 16; return v.f;
}
__device__ __forceinline__ unsigned short f2bflo(float a) {
    return f2bf(a - bf2f(f2bf(a)));
}
__device__ __forceinline__ unsigned pk2(unsigned short lo, unsigned short hi) {
    return (unsigned)lo | ((unsigned)hi << 16);
}

// Tanh-form gelu, native exp2/rcp (R11). |delta| vs erf-gelu ~3e-4.
// NOTE (R15 lesson): keep all WEIGHT reads as scalar float loads — vector-
// typed (float2/float4) loads from uniform addresses defeat s_load
// scalarization and regress 2.3x.
__device__ __forceinline__ float gelu_fast(float v) {
    float u = v * v;
    float inner = v * fmaf(0.0356774081f, u, 0.7978845608f);
    float e = __builtin_amdgcn_exp2f(inner * 2.8853900818f);
    float r = __builtin_amdgcn_rcpf(e + 1.0f);
    return fmaf(-v, r, v);
}

// ---------------- k_prep: max-reduce + zero cP + build w1T(global) ----------
__global__ __launch_bounds__(256) void k_prep(const float* __restrict__ pd,
                                              const float* __restrict__ w1,
                                              float* __restrict__ invmax,
                                              float* __restrict__ cP,
                                              unsigned short* __restrict__ w1Tg) {
    int bx = blockIdx.x;
    if (bx == 0) {
        __shared__ float red[256];
        int t = threadIdx.x;
        float m = -1e30f;
        for (int i = t; i < SS; i += 256) m = fmaxf(m, pd[i]);
        red[t] = m; __syncthreads();
        for (int off = 128; off > 0; off >>= 1) {
            if (t < off) red[t] = fmaxf(red[t], red[t + off]);
            __syncthreads();
        }
        if (t == 0) invmax[0] = 1.0f / red[0];
    } else if (bx <= 1280) {
        int idx = (bx - 1) * 256 + threadIdx.x;   // 1280*256 float4 = 4*16*32*640 floats
        float4 z = {0.f, 0.f, 0.f, 0.f};
        ((float4*)cP)[idx] = z;
    } else {
        for (int idx = threadIdx.x; idx < HH * 64; idx += 256) {
            int j = idx >> 6, k = idx & 63;
            unsigned short r = 0;
            if (k < CC) r = f2bf(w1[k * HH + j]);
            else if (k >= 32 && k < 32 + CC) r = f2bflo(w1[(k - 32) * HH + j]);
            w1Tg[idx] = r;
        }
    }
}

// ---------------- shared DFT tail: LDS-staged MFMA partial DFT --------------
__device__ __forceinline__ void dft_phase(unsigned short* sh_hA, unsigned short* sh_ph,
                                          int tid, float* cPdst) {
    int wave = tid >> 6, lane = tid & 63;
    int quad = lane >> 4, frow = lane & 15;
    floatx4 acc00 = {0.f,0.f,0.f,0.f}, acc01 = {0.f,0.f,0.f,0.f};
    floatx4 acc10 = {0.f,0.f,0.f,0.f}, acc11 = {0.f,0.f,0.f,0.f};
    int kb = wave * 64 + quad * 8;
    #pragma unroll
    for (int kc = 0; kc < 2; ++kc) {
        int k = kb + kc * 32;
        short8 a0 = *(const short8*)(sh_hA + frow * RP + k);
        short8 a1 = *(const short8*)(sh_hA + (16 + frow) * RP + k);
        short8 bc = *(const short8*)(sh_ph + frow * RP + k);
        short8 bs = *(const short8*)(sh_ph + (16 + frow) * RP + k);
        acc00 = __builtin_amdgcn_mfma_f32_16x16x32_bf16(a0, bc, acc00, 0, 0, 0);
        acc01 = __builtin_amdgcn_mfma_f32_16x16x32_bf16(a0, bs, acc01, 0, 0, 0);
        acc10 = __builtin_amdgcn_mfma_f32_16x16x32_bf16(a1, bc, acc10, 0, 0, 0);
        acc11 = __builtin_amdgcn_mfma_f32_16x16x32_bf16(a1, bs, acc11, 0, 0, 0);
    }
    __syncthreads();
    float* red = (float*)sh_hA;
    #pragma unroll
    for (int r = 0; r < 4; ++r) {
        red[wave * 1024 + 0 * 256 + r * 64 + lane] = acc00[r];
        red[wave * 1024 + 1 * 256 + r * 64 + lane] = acc01[r];
        red[wave * 1024 + 2 * 256 + r * 64 + lane] = acc10[r];
        red[wave * 1024 + 3 * 256 + r * 64 + lane] = acc11[r];
    }
    __syncthreads();
    #pragma unroll
    for (int ii = 0; ii < 4; ++ii) {
        int idx = ii * 256 + tid;
        float v = red[idx] + red[1024 + idx] + red[2048 + idx] + red[3072 + idx];
        int f = idx >> 8;
        int r = (idx >> 6) & 3, ln = idx & 63;
        int o = (f >> 1) * 16 + (ln >> 4) * 4 + r;   // D row = quad*4+reg
        int m = ln & 15;                              // D col = lane&15
        if (o < CC) atomicAdd(cPdst + (f & 1) * 320 + o * 16 + m, v);
    }
}

// ---------------- k_fc0_dft: h2 (paired bf16 dwords) = fc0; DFT partials ----
__global__ __launch_bounds__(256, 4) void k_fc0_dft(const float* __restrict__ x,
        const float* __restrict__ pd, const float* __restrict__ w,
        const float* __restrict__ bias, const float* __restrict__ invmax,
        unsigned* __restrict__ h2, float* __restrict__ cP0) {
    __shared__ __align__(16) unsigned short sh_hA[32 * RP];
    __shared__ __align__(16) unsigned short sh_ph[32 * RP];
    int tid = threadIdx.x;
    {
        unsigned* z = (unsigned*)(sh_hA + CC * RP);
        for (int i = tid; i < (32 - CC) * RP / 2; i += 256) z[i] = 0;
    }
    int b = blockIdx.y;
    int s = blockIdx.x * 256 + tid;
    float xv = x[(size_t)b * SS + s];
    float g  = pd[s] * invmax[0];
    unsigned* hp2 = h2 + (size_t)b * (CC / 2) * SS + s;
    float u = (float)s * (1.0f / 32768.0f);
    float s1, c1; sincospif(u, &s1, &c1);
    float cm = 1.0f, sm = 0.0f;
    #pragma unroll
    for (int m = 0; m < NM; ++m) {
        sh_ph[m * RP + tid]        = f2bf(cm);
        sh_ph[(16 + m) * RP + tid] = f2bf(sm);
        float cn = cm * c1 - sm * s1;
        sm = sm * c1 + cm * s1;
        cm = cn;
    }
    #pragma unroll
    for (int p = 0; p < CC / 2; ++p) {
        int c0 = 2 * p, c1i = 2 * p + 1;
        float v0 = xv * w[c0]  + g * w[CC + c0]  + bias[c0];
        float v1 = xv * w[c1i] + g * w[CC + c1i] + bias[c1i];
        unsigned short a0 = f2bf(v0), a1 = f2bf(v1);
        hp2[(size_t)p * SS] = (unsigned)a0 | ((unsigned)a1 << 16);
        sh_hA[c0 * RP + tid]  = a0;
        sh_hA[c1i * RP + tid] = a1;
    }
    __syncthreads();
    dft_phase(sh_hA, sh_ph, tid, cP0 + ((size_t)(blockIdx.x & (NSLOT - 1)) * BB + b) * 640);
}

// ---------------- k_point_dft (layers 0..2): MFMA point-op + next-layer DFT -
// R17: point-op as 256x20 GEMM, K=64 hi + K=32 trig-lo, 5 MFMA / 16x16 tile.
__global__ __launch_bounds__(256, 3) void k_point_dft(unsigned* __restrict__ h2,
        const unsigned short* __restrict__ Bpk,
        float* __restrict__ cPn) {
    __shared__ __align__(16) unsigned short AST[256 * 64 + 256 * 32];   // 48 KB
    unsigned short* ALO   = AST + 256 * 64;
    unsigned short* sh_hA = AST;                 // aliases, valid after barrier
    unsigned short* sh_ph = AST + 32 * RP;
    int tid = threadIdx.x;
    int b = blockIdx.y;
    int s = blockIdx.x * 256 + tid;

    // ---- phase A: trig + old-h load + A-row staging -------------------
    float u = (float)s * (1.0f / 32768.0f);
    float s1, c1; sincospif(u, &s1, &c1);
    float cm[NM], sm[NM];
    cm[0] = 1.0f; sm[0] = 0.0f;
    #pragma unroll
    for (int m = 1; m < NM; ++m) {
        cm[m] = cm[m - 1] * c1 - sm[m - 1] * s1;
        sm[m] = sm[m - 1] * c1 + cm[m - 1] * s1;
    }
    const unsigned* hp2r = h2 + (size_t)b * (CC / 2) * SS + s;
    unsigned hw[CC / 2];
    #pragma unroll
    for (int p = 0; p < CC / 2; ++p) hw[p] = hp2r[(size_t)p * SS];

    unsigned short chi[NM], shi[NM], clo[NM], slo[NM];
    #pragma unroll
    for (int m = 0; m < NM; ++m) {
        chi[m] = f2bf(cm[m]);  clo[m] = f2bf(cm[m] - bf2f(chi[m]));
        shi[m] = f2bf(sm[m]);  slo[m] = f2bf(sm[m] - bf2f(shi[m]));
    }
    {   // hi row: 8 swizzled 16B chunks
        uint4 q;
        int sw = tid & 7;
        unsigned* base = (unsigned*)(AST + tid * 64);
        q = (uint4){hw[0], hw[1], hw[2], hw[3]};
        *(uint4*)(base + ((0 ^ sw) << 2)) = q;
        q = (uint4){hw[4], hw[5], hw[6], hw[7]};
        *(uint4*)(base + ((1 ^ sw) << 2)) = q;
        q = (uint4){hw[8], hw[9], 0x00003F80u, 0u};        // elems 16..23: h16..19, ONE(bias), 0
        *(uint4*)(base + ((2 ^ sw) << 2)) = q;
        q = (uint4){0u, 0u, 0u, 0u};
        *(uint4*)(base + ((3 ^ sw) << 2)) = q;
        q = (uint4){pk2(chi[0],chi[1]), pk2(chi[2],chi[3]), pk2(chi[4],chi[5]), pk2(chi[6],chi[7])};
        *(uint4*)(base + ((4 ^ sw) << 2)) = q;
        q = (uint4){pk2(chi[8],chi[9]), pk2(chi[10],chi[11]), pk2(chi[12],chi[13]), pk2(chi[14],chi[15])};
        *(uint4*)(base + ((5 ^ sw) << 2)) = q;
        q = (uint4){pk2(shi[0],shi[1]), pk2(shi[2],shi[3]), pk2(shi[4],shi[5]), pk2(shi[6],shi[7])};
        *(uint4*)(base + ((6 ^ sw) << 2)) = q;
        q = (uint4){pk2(shi[8],shi[9]), pk2(shi[10],shi[11]), pk2(shi[12],shi[13]), pk2(shi[14],shi[15])};
        *(uint4*)(base + ((7 ^ sw) << 2)) = q;
        // lo row: 4 swizzled chunks [cm_lo(16) | sm_lo(16)]
        int sw3 = tid & 3;
        unsigned* lbase = (unsigned*)(ALO + tid * 32);
        q = (uint4){pk2(clo[0],clo[1]), pk2(clo[2],clo[3]), pk2(clo[4],clo[5]), pk2(clo[6],clo[7])};
        *(uint4*)(lbase + ((0 ^ sw3) << 2)) = q;
        q = (uint4){pk2(clo[8],clo[9]), pk2(clo[10],clo[11]), pk2(clo[12],clo[13]), pk2(clo[14],clo[15])};
        *(uint4*)(lbase + ((1 ^ sw3) << 2)) = q;
        q = (uint4){pk2(slo[0],slo[1]), pk2(slo[2],slo[3]), pk2(slo[4],slo[5]), pk2(slo[6],slo[7])};
        *(uint4*)(lbase + ((2 ^ sw3) << 2)) = q;
        q = (uint4){pk2(slo[8],slo[9]), pk2(slo[10],slo[11]), pk2(slo[12],slo[13]), pk2(slo[14],slo[15])};
        *(uint4*)(lbase + ((3 ^ sw3) << 2)) = q;
    }
    __syncthreads();

    // ---- phase B: MFMA point-op, gelu, pack ---------------------------
    int wave = tid >> 6, lane = tid & 63, col = lane & 15, quad = lane >> 4;
    const unsigned short* Bp = Bpk + (size_t)b * 4096;
    short8 bh0[2], bh1[2], bl0[2], bl1[2];
    #pragma unroll
    for (int nt = 0; nt < 2; ++nt) {
        int o = nt * 16 + col;
        bh0[nt] = *(const short8*)(Bp + o * 64 + quad * 8);
        bh1[nt] = *(const short8*)(Bp + o * 64 + 32 + quad * 8);
        bl0[nt] = *(const short8*)(Bp + 2048 + o * 64 + quad * 8);
        bl1[nt] = *(const short8*)(Bp + 2048 + o * 64 + 32 + quad * 8);
    }
    unsigned packres[2][8];
    #pragma unroll
    for (int mt = 0; mt < 4; ++mt) {
        int ar = wave * 64 + mt * 16 + col;
        int sw = ar & 7;
        const unsigned short* abase = AST + ar * 64;
        short8 ah0 = *(const short8*)(abase + ((quad ^ sw) << 3));
        short8 ah1 = *(const short8*)(abase + (((4 + quad) ^ sw) << 3));
        short8 al  = *(const short8*)(ALO + ar * 32 + ((quad ^ (ar & 3)) << 3));
        #pragma unroll
        for (int nt = 0; nt < 2; ++nt) {
            floatx4 a = {0.f, 0.f, 0.f, 0.f};
            a = __builtin_amdgcn_mfma_f32_16x16x32_bf16(ah0, bh0[nt], a, 0, 0, 0);
            a = __builtin_amdgcn_mfma_f32_16x16x32_bf16(ah1, bh1[nt], a, 0, 0, 0);
            a = __builtin_amdgcn_mfma_f32_16x16x32_bf16(ah0, bl0[nt], a, 0, 0, 0);
            a = __builtin_amdgcn_mfma_f32_16x16x32_bf16(ah1, bl1[nt], a, 0, 0, 0);
            a = __builtin_amdgcn_mfma_f32_16x16x32_bf16(al,  bh1[nt], a, 0, 0, 0);
            unsigned short r0 = f2bf(gelu_fast(a[0]));
            unsigned short r1 = f2bf(gelu_fast(a[1]));
            unsigned short r2 = f2bf(gelu_fast(a[2]));
            unsigned short r3 = f2bf(gelu_fast(a[3]));
            packres[nt][mt * 2 + 0] = pk2(r0, r1);
            packres[nt][mt * 2 + 1] = pk2(r2, r3);
        }
    }
    __syncthreads();   // all A-stage reads done; LDS now re-used as sh_hA/sh_ph

    // ---- phase C: scatter h_new to sh_hA, write sh_ph, store h2 -------
    {
        unsigned* z = (unsigned*)(sh_hA + CC * RP);
        #pragma unroll
        for (int i = tid; i < (32 - CC) * RP / 2; i += 256) z[i] = 0;
    }
    #pragma unroll
    for (int m = 0; m < NM; ++m) {
        sh_ph[m * RP + tid]        = f2bf(cm[m]);
        sh_ph[(16 + m) * RP + tid] = f2bf(sm[m]);
    }
    unsigned* h2b = h2 + (size_t)b * (CC / 2) * SS + blockIdx.x * 256;
    #pragma unroll
    for (int nt = 0; nt < 2; ++nt) {
        int o = nt * 16 + col;
        bool valid = (o < CC);
        #pragma unroll
        for (int mt = 0; mt < 4; ++mt) {
            int sb = wave * 64 + mt * 16 + quad * 4;
            #pragma unroll
            for (int rp = 0; rp < 2; ++rp) {
                unsigned dw = packres[nt][mt * 2 + rp];
                if (valid) {
                    sh_hA[o * RP + sb + 2 * rp]     = (unsigned short)(dw & 0xFFFFu);
                    sh_hA[o * RP + sb + 2 * rp + 1] = (unsigned short)(dw >> 16);
                }
                unsigned pdw = __shfl_xor(dw, 1, 64);
                if (valid && !(col & 1)) {
                    int p = o >> 1;
                    h2b[(size_t)p * SS + sb + 2 * rp]     = (dw & 0xFFFFu) | (pdw << 16);
                    h2b[(size_t)p * SS + sb + 2 * rp + 1] = (dw >> 16) | (pdw & 0xFFFF0000u);
                }
            }
        }
    }
    __syncthreads();
    dft_phase(sh_hA, sh_ph, tid, cPn + ((size_t)(blockIdx.x & (NSLOT - 1)) * BB + b) * 640);
}

// ---------------- k_mix: partial reduce + complex mixing + B-panel pack -----
__global__ __launch_bounds__(320) void k_mix(const float* __restrict__ cP,
                                             const float* __restrict__ wre, const float* __restrict__ wim,
                                             const float* __restrict__ ww, const float* __restrict__ wb,
                                             float* __restrict__ cA, float* __restrict__ cB,
                                             unsigned short* __restrict__ Bpk) {
    int b = blockIdx.x, tid = threadIdx.x;
    __shared__ float PQ[640];
    const float* base = cP + (size_t)b * 640;
    int i = tid >> 4, m = tid & 15;
    float sP = 0.f, sQ = 0.f;
    #pragma unroll 4
    for (int sl = 0; sl < NSLOT; ++sl) {
        sP += base[(size_t)sl * BB * 640 + tid];
        sQ += base[(size_t)sl * BB * 640 + 320 + tid];
    }
    PQ[i * 32 + m]      = sP;
    PQ[i * 32 + 16 + m] = sQ;
    __syncthreads();
    int o = i;
    float reY = 0.f, imY = 0.f;
    #pragma unroll
    for (int c = 0; c < CC; ++c) {
        float P = PQ[c * 32 + m], Q = PQ[c * 32 + 16 + m];
        float wr = wre[(size_t)(c * CC + o) * NM + m];
        float wi = wim[(size_t)(c * CC + o) * NM + m];
        reY += P * wr + Q * wi;                // X = P - iQ
        imY += P * wi - Q * wr;
    }
    const float invS = 1.0f / (float)SS;
    float a, bb;
    if (m == 0) { a = reY * invS; bb = 0.0f; } // irfft drops Im(DC)
    else        { a = 2.0f * reY * invS; bb = -2.0f * imY * invS; }
    cA[(size_t)(b * CC + o) * NM + m] = a;
    cB[(size_t)(b * CC + o) * NM + m] = bb;

    // ---- pack B panels for the MFMA point-op (per-b) ------------------
    unsigned short* Bp = Bpk + (size_t)b * 4096;
    for (int idx = tid; idx < 640; idx += 320) {       // o<20, k 0..31
        int o8 = idx >> 5, k = idx & 31;
        float v = 0.f;
        if (k < CC) v = ww[o8 * CC + k];
        else if (k == CC) v = wb[o8];
        Bp[o8 * 64 + k]        = f2bf(v);
        Bp[2048 + o8 * 64 + k] = f2bflo(v);
    }
    for (int idx = tid; idx < 768; idx += 320) {       // o 20..31: zero rows
        int o8 = 20 + (idx >> 6), k = idx & 63;
        Bp[o8 * 64 + k] = 0;
        Bp[2048 + o8 * 64 + k] = 0;
    }
    Bp[o * 64 + 32 + m]        = f2bf(a);
    Bp[o * 64 + 48 + m]        = f2bf(bb);
    Bp[2048 + o * 64 + 32 + m] = f2bflo(a);
    Bp[2048 + o * 64 + 48 + m] = f2bflo(bb);
}

// ---------------- k_point_final: MFMA layer-3 point op + fc1 + gelu + fc2 ---
// R18: layer-3 point-op ported to the R17 5-MFMA scheme. D-fragment
// (row=quad*4+r, col=o) -> hT row-major hi/lo via shfl channel-pairing +
// swizzled ds_write_b32 (2-way bank alias max). hT pad channels 20..31 stay
// garbage: w1Tg rows k in [20,32)+[52,64) are ZERO, so they never contribute.
// LDS = 48KB (AST 32K hi + ALO 16K lo, hT aliases AST) -> 3 blocks/CU.
__global__ __launch_bounds__(256, 3) void k_point_final(const unsigned* __restrict__ h2,
        const unsigned short* __restrict__ Bpk,
        const unsigned short* __restrict__ w1Tg, const float* __restrict__ b1,
        const float* __restrict__ w2, const float* __restrict__ b2,
        float* __restrict__ out) {
    __shared__ __align__(16) unsigned short AST[256 * 64 + 256 * 32];   // 48 KB
    unsigned short* ALO = AST + 256 * 64;
    unsigned short* hT  = AST;           // aliased after phase-B barrier
    int tid = threadIdx.x;
    int b = blockIdx.y;
    int s = blockIdx.x * 256 + tid;

    // ---- phase A: trig + h load + A-row staging (same as k_point_dft) --
    float u = (float)s * (1.0f / 32768.0f);
    float s1, c1; sincospif(u, &s1, &c1);
    float cm[NM], sm[NM];
    cm[0] = 1.0f; sm[0] = 0.0f;
    #pragma unroll
    for (int m = 1; m < NM; ++m) {
        cm[m] = cm[m - 1] * c1 - sm[m - 1] * s1;
        sm[m] = sm[m - 1] * c1 + cm[m - 1] * s1;
    }
    const unsigned* hp2r = h2 + (size_t)b * (CC / 2) * SS + s;
    unsigned hw[CC / 2];
    #pragma unroll
    for (int p = 0; p < CC / 2; ++p) hw[p] = hp2r[(size_t)p * SS];

    unsigned short chi[NM], shi[NM], clo[NM], slo[NM];
    #pragma unroll
    for (int m = 0; m < NM; ++m) {
        chi[m] = f2bf(cm[m]);  clo[m] = f2bf(cm[m] - bf2f(chi[m]));
        shi[m] = f2bf(sm[m]);  slo[m] = f2bf(sm[m] - bf2f(shi[m]));
    }
    {
        uint4 q;
        int sw = tid & 7;
        unsigned* base = (unsigned*)(AST + tid * 64);
        q = (uint4){hw[0], hw[1], hw[2], hw[3]};
        *(uint4*)(base + ((0 ^ sw) << 2)) = q;
        q = (uint4){hw[4], hw[5], hw[6], hw[7]};
        *(uint4*)(base + ((1 ^ sw) << 2)) = q;
        q = (uint4){hw[8], hw[9], 0x00003F80u, 0u};
        *(uint4*)(base + ((2 ^ sw) << 2)) = q;
        q = (uint4){0u, 0u, 0u, 0u};
        *(uint4*)(base + ((3 ^ sw) << 2)) = q;
        q = (uint4){pk2(chi[0],chi[1]), pk2(chi[2],chi[3]), pk2(chi[4],chi[5]), pk2(chi[6],chi[7])};
        *(uint4*)(base + ((4 ^ sw) << 2)) = q;
        q = (uint4){pk2(chi[8],chi[9]), pk2(chi[10],chi[11]), pk2(chi[12],chi[13]), pk2(chi[14],chi[15])};
        *(uint4*)(base + ((5 ^ sw) << 2)) = q;
        q = (uint4){pk2(shi[0],shi[1]), pk2(shi[2],shi[3]), pk2(shi[4],shi[5]), pk2(shi[6],shi[7])};
        *(uint4*)(base + ((6 ^ sw) << 2)) = q;
        q = (uint4){pk2(shi[8],shi[9]), pk2(shi[10],shi[11]), pk2(shi[12],shi[13]), pk2(shi[14],shi[15])};
        *(uint4*)(base + ((7 ^ sw) << 2)) = q;
        int sw3 = tid & 3;
        unsigned* lbase = (unsigned*)(ALO + tid * 32);
        q = (uint4){pk2(clo[0],clo[1]), pk2(clo[2],clo[3]), pk2(clo[4],clo[5]), pk2(clo[6],clo[7])};
        *(uint4*)(lbase + ((0 ^ sw3) << 2)) = q;
        q = (uint4){pk2(clo[8],clo[9]), pk2(clo[10],clo[11]), pk2(clo[12],clo[13]), pk2(clo[14],clo[15])};
        *(uint4*)(lbase + ((1 ^ sw3) << 2)) = q;
        q = (uint4){pk2(slo[0],slo[1]), pk2(slo[2],slo[3]), pk2(slo[4],slo[5]), pk2(slo[6],slo[7])};
        *(uint4*)(lbase + ((2 ^ sw3) << 2)) = q;
        q = (uint4){pk2(slo[8],slo[9]), pk2(slo[10],slo[11]), pk2(slo[12],slo[13]), pk2(slo[14],slo[15])};
        *(uint4*)(lbase + ((3 ^ sw3) << 2)) = q;
    }
    __syncthreads();

    // ---- phase B: point-op MFMA (no gelu), f32 results in regs ---------
    int wave = tid >> 6, lane = tid & 63, col = lane & 15, quad = lane >> 4;
    const unsigned short* Bp = Bpk + (size_t)b * 4096;
    short8 bh0[2], bh1[2], bl0[2], bl1[2];
    #pragma unroll
    for (int nt = 0; nt < 2; ++nt) {
        int o = nt * 16 + col;
        bh0[nt] = *(const short8*)(Bp + o * 64 + quad * 8);
        bh1[nt] = *(const short8*)(Bp + o * 64 + 32 + quad * 8);
        bl0[nt] = *(const short8*)(Bp + 2048 + o * 64 + quad * 8);
        bl1[nt] = *(const short8*)(Bp + 2048 + o * 64 + 32 + quad * 8);
    }
    float res[2][4][4];   // [nt][mt][r] — all statically indexed
    #pragma unroll
    for (int mt = 0; mt < 4; ++mt) {
        int ar = wave * 64 + mt * 16 + col;
        int sw = ar & 7;
        const unsigned short* abase = AST + ar * 64;
        short8 ah0 = *(const short8*)(abase + ((quad ^ sw) << 3));
        short8 ah1 = *(const short8*)(abase + (((4 + quad) ^ sw) << 3));
        short8 al  = *(const short8*)(ALO + ar * 32 + ((quad ^ (ar & 3)) << 3));
        #pragma unroll
        for (int nt = 0; nt < 2; ++nt) {
            floatx4 a = {0.f, 0.f, 0.f, 0.f};
            a = __builtin_amdgcn_mfma_f32_16x16x32_bf16(ah0, bh0[nt], a, 0, 0, 0);
            a = __builtin_amdgcn_mfma_f32_16x16x32_bf16(ah1, bh1[nt], a, 0, 0, 0);
            a = __builtin_amdgcn_mfma_f32_16x16x32_bf16(ah0, bl0[nt], a, 0, 0, 0);
            a = __builtin_amdgcn_mfma_f32_16x16x32_bf16(ah1, bl1[nt], a, 0, 0, 0);
            a = __builtin_amdgcn_mfma_f32_16x16x32_bf16(al,  bh1[nt], a, 0, 0, 0);
            #pragma unroll
            for (int r = 0; r < 4; ++r) res[nt][mt][r] = a[r];
        }
    }
    __syncthreads();   // AST/ALO reads done; LDS region re-used as hT

    // ---- phase C: build hT rows (hi/lo split, channel-pair dwords) -----
    #pragma unroll
    for (int mt = 0; mt < 4; ++mt) {
        #pragma unroll
        for (int nt = 0; nt < 2; ++nt) {
            int o = nt * 16 + col;
            int dwi = o >> 1;
            int chunk = o >> 3;
            bool wr = !(col & 1) && (o < CC);
            #pragma unroll
            for (int r = 0; r < 4; ++r) {
                float av = res[nt][mt][r];
                unsigned short hi = f2bf(av);
                unsigned short lo = f2bf(av - bf2f(hi));
                unsigned pklh = pk2(hi, lo);
                unsigned part = __shfl_xor(pklh, 1, 64);
                if (wr) {
                    int row = wave * 64 + mt * 16 + quad * 4 + r;
                    int sw = row & 7;
                    unsigned* rb = (unsigned*)(hT + row * WP);
                    rb[((chunk ^ sw) << 2) + (dwi & 3)]       = (pklh & 0xFFFFu) | (part << 16);
                    rb[(((chunk + 4) ^ sw) << 2) + (dwi & 3)] = (pklh >> 16) | (part & 0xFFFF0000u);
                }
            }
        }
    }
    __syncthreads();

    // ---- fc1 MFMA + gelu + fc2 (unchanged from R16) --------------------
    short8 bhi[8], blo[8];
    #pragma unroll
    for (int nt = 0; nt < 8; ++nt) {
        bhi[nt] = *(const short8*)(w1Tg + (size_t)(nt * 16 + col) * 64 + quad * 8);
        blo[nt] = *(const short8*)(w1Tg + (size_t)(nt * 16 + col) * 64 + 32 + quad * 8);
    }
    float lb1r[8], w2r[8];
    #pragma unroll
    for (int nt = 0; nt < 8; ++nt) { lb1r[nt] = b1[nt * 16 + col]; w2r[nt] = w2[nt * 16 + col]; }
    float b2v = b2[0];
    #pragma unroll
    for (int mt = 0; mt < 4; ++mt) {
        int srow = wave * 64 + mt * 16 + col;     // A row m = lane&15
        int sw = srow & 7;
        short8 ahi = *(const short8*)(hT + srow * WP + ((quad ^ sw) << 3));
        short8 alo = *(const short8*)(hT + srow * WP + (((quad ^ sw) ^ 4) << 3));
        float part[4] = {0.f, 0.f, 0.f, 0.f};
        #pragma unroll
        for (int nt = 0; nt < 8; ++nt) {
            floatx4 a = {0.f, 0.f, 0.f, 0.f};
            a = __builtin_amdgcn_mfma_f32_16x16x32_bf16(ahi, bhi[nt], a, 0, 0, 0);
            a = __builtin_amdgcn_mfma_f32_16x16x32_bf16(ahi, blo[nt], a, 0, 0, 0);
            a = __builtin_amdgcn_mfma_f32_16x16x32_bf16(alo, bhi[nt], a, 0, 0, 0);
            #pragma unroll
            for (int r = 0; r < 4; ++r) {
                float t = gelu_fast(a[r] + lb1r[nt]);
                part[r] += t * w2r[nt];
            }
        }
        #pragma unroll
        for (int r = 0; r < 4; ++r) {
            float p = part[r];
            p += __shfl_xor(p, 1, 64);
            p += __shfl_xor(p, 2, 64);
            p += __shfl_xor(p, 4, 64);
            p += __shfl_xor(p, 8, 64);
            if (col == 0) {
                int row = wave * 64 + mt * 16 + quad * 4 + r;   // dead rows of this tile
                *(float*)(&hT[row * WP + ((row & 7) << 3)]) = p + b2v;
            }
        }
    }
    __syncthreads();
    out[(size_t)b * SS + blockIdx.x * 256 + tid] = *(const float*)(&hT[tid * WP + ((tid & 7) << 3)]);
}

extern "C" void kernel_launch(void* const* d_in, const int* in_sizes, int n_in,
                              void* d_out, int out_size, void* d_ws, size_t ws_size,
                              hipStream_t stream) {
    (void)in_sizes; (void)n_in; (void)out_size; (void)ws_size;
    const float* x    = (const float*)d_in[0];
    const float* pd   = (const float*)d_in[1];
    const float* fc0w = (const float*)d_in[2];
    const float* fc0b = (const float*)d_in[3];
    const float* fc1w = (const float*)d_in[4];
    const float* fc1b = (const float*)d_in[5];
    const float* fc2w = (const float*)d_in[6];
    const float* fc2b = (const float*)d_in[7];

    char* ws = (char*)d_ws;
    unsigned* h2 = (unsigned*)ws;
    size_t off = (size_t)BB * (CC / 2) * SS * 4;                      // 83.9 MB (paired bf16)
    float* cP = (float*)(ws + off); off += (size_t)4 * NSLOT * BB * 640 * 4;  // 5.24 MB
    float* cA = (float*)(ws + off); off += (size_t)BB * CC * NM * 4;
    float* cB = (float*)(ws + off); off += (size_t)BB * CC * NM * 4;
    float* invmax = (float*)(ws + off); off += 256;
    unsigned short* w1Tg = (unsigned short*)(ws + off); off += (size_t)HH * 64 * 2;  // 16 KB
    unsigned short* Bpk  = (unsigned short*)(ws + off); off += (size_t)BB * 4096 * 2; // 256 KB
    const size_t CPL = (size_t)NSLOT * BB * 640;   // floats per layer-slot set

    dim3 gBS(SS / 256, BB);

    k_prep<<<1282, 256, 0, stream>>>(pd, fc1w, invmax, cP, w1Tg);
    k_fc0_dft<<<gBS, 256, 0, stream>>>(x, pd, fc0w, fc0b, invmax, h2, cP);

    for (int l = 0; l < 3; ++l) {
        const float* wre = (const float*)d_in[8 + 4 * l];
        const float* wim = (const float*)d_in[9 + 4 * l];
        const float* ww  = (const float*)d_in[10 + 4 * l];
        const float* wb  = (const float*)d_in[11 + 4 * l];
        k_mix<<<BB, 320, 0, stream>>>(cP + (size_t)l * CPL, wre, wim, ww, wb, cA, cB, Bpk);
        k_point_dft<<<gBS, 256, 0, stream>>>(h2, Bpk, cP + (size_t)(l + 1) * CPL);
    }
    {   // layer 3 fused with fc1/gelu/fc2
        const float* wre = (const float*)d_in[20];
        const float* wim = (const float*)d_in[21];
        const float* ww  = (const float*)d_in[22];
        const float* wb  = (const float*)d_in[23];
        k_mix<<<BB, 320, 0, stream>>>(cP + (size_t)3 * CPL, wre, wim, ww, wb, cA, cB, Bpk);
        k_point_final<<<gBS, 256, 0, stream>>>(h2, Bpk,
                                               w1Tg, fc1b, fc2w, fc2b, (float*)d_out);
    }
}

// Round 5
// 548.767 us; speedup vs baseline: 1.2729x; 1.1815x over previous
//
#include <hip/hip_runtime.h>
#include <math.h>

#define BB 32
#define SS 65536
#define CC 20
#define NM 16
#define HH 128
#define RP 264   // DFT LDS row pitch (bf16 elems)
#define WP 64    // hT row pitch (bf16 elems): 8x short8 payload, XOR-swizzled chunks
#define NSLOT 16

using short8  = __attribute__((ext_vector_type(8))) short;
using floatx4 = __attribute__((ext_vector_type(4))) float;

__device__ __forceinline__ unsigned short f2bf(float f) {
    union { float f; unsigned u; } v; v.f = f;
    unsigned u = v.u;
    return (unsigned short)((u + 0x7FFFu + ((u >> 16) & 1u)) >> 16);   // RNE
}
__device__ __forceinline__ float bf2f(unsigned short h) {
    union { unsigned u; float f; } v; v.u = ((unsigned)h) << 16; return v.f;
}
__device__ __forceinline__ unsigned short f2bflo(float a) {
    return f2bf(a - bf2f(f2bf(a)));
}
__device__ __forceinline__ unsigned pk2(unsigned short lo, unsigned short hi) {
    return (unsigned)lo | ((unsigned)hi << 16);
}

// Tanh-form gelu, native exp2/rcp (R11). |delta| vs erf-gelu ~3e-4.
// NOTE (R15 lesson): keep all WEIGHT reads as scalar float loads — vector-
// typed (float2/float4) loads from uniform addresses defeat s_load
// scalarization and regress 2.3x.
__device__ __forceinline__ float gelu_fast(float v) {
    float u = v * v;
    float inner = v * fmaf(0.0356774081f, u, 0.7978845608f);
    float e = __builtin_amdgcn_exp2f(inner * 2.8853900818f);
    float r = __builtin_amdgcn_rcpf(e + 1.0f);
    return fmaf(-v, r, v);
}

// R19: shared A-row staging — [h(20)|1|pad(11)|cm_hi(16)|sm_hi(16)], XOR-chunk
// swizzled. Row tid written by thread tid (wave-local: no barrier needed
// before same-wave phase-B reads; LDS ops per wave execute in issue order).
__device__ __forceinline__ void stage_A(unsigned short* AST, int tid,
                                        const unsigned* hw,
                                        const unsigned short* chi,
                                        const unsigned short* shi) {
    uint4 q;
    int sw = tid & 7;
    unsigned* base = (unsigned*)(AST + tid * 64);
    q = (uint4){hw[0], hw[1], hw[2], hw[3]};
    *(uint4*)(base + ((0 ^ sw) << 2)) = q;
    q = (uint4){hw[4], hw[5], hw[6], hw[7]};
    *(uint4*)(base + ((1 ^ sw) << 2)) = q;
    q = (uint4){hw[8], hw[9], 0x00003F80u, 0u};        // h16..19, ONE(bias), 0
    *(uint4*)(base + ((2 ^ sw) << 2)) = q;
    q = (uint4){0u, 0u, 0u, 0u};
    *(uint4*)(base + ((3 ^ sw) << 2)) = q;
    q = (uint4){pk2(chi[0],chi[1]), pk2(chi[2],chi[3]), pk2(chi[4],chi[5]), pk2(chi[6],chi[7])};
    *(uint4*)(base + ((4 ^ sw) << 2)) = q;
    q = (uint4){pk2(chi[8],chi[9]), pk2(chi[10],chi[11]), pk2(chi[12],chi[13]), pk2(chi[14],chi[15])};
    *(uint4*)(base + ((5 ^ sw) << 2)) = q;
    q = (uint4){pk2(shi[0],shi[1]), pk2(shi[2],shi[3]), pk2(shi[4],shi[5]), pk2(shi[6],shi[7])};
    *(uint4*)(base + ((6 ^ sw) << 2)) = q;
    q = (uint4){pk2(shi[8],shi[9]), pk2(shi[10],shi[11]), pk2(shi[12],shi[13]), pk2(shi[14],shi[15])};
    *(uint4*)(base + ((7 ^ sw) << 2)) = q;
}

// ---------------- k_prep: max-reduce + zero cP + build w1T(global) ----------
__global__ __launch_bounds__(256) void k_prep(const float* __restrict__ pd,
                                              const float* __restrict__ w1,
                                              float* __restrict__ invmax,
                                              float* __restrict__ cP,
                                              unsigned short* __restrict__ w1Tg) {
    int bx = blockIdx.x;
    if (bx == 0) {
        __shared__ float red[256];
        int t = threadIdx.x;
        float m = -1e30f;
        for (int i = t; i < SS; i += 256) m = fmaxf(m, pd[i]);
        red[t] = m; __syncthreads();
        for (int off = 128; off > 0; off >>= 1) {
            if (t < off) red[t] = fmaxf(red[t], red[t + off]);
            __syncthreads();
        }
        if (t == 0) invmax[0] = 1.0f / red[0];
    } else if (bx <= 1280) {
        int idx = (bx - 1) * 256 + threadIdx.x;   // 1280*256 float4 = 4*16*32*640 floats
        float4 z = {0.f, 0.f, 0.f, 0.f};
        ((float4*)cP)[idx] = z;
    } else {
        for (int idx = threadIdx.x; idx < HH * 64; idx += 256) {
            int j = idx >> 6, k = idx & 63;
            unsigned short r = 0;
            if (k < CC) r = f2bf(w1[k * HH + j]);
            else if (k >= 32 && k < 32 + CC) r = f2bflo(w1[(k - 32) * HH + j]);
            w1Tg[idx] = r;
        }
    }
}

// ---------------- shared DFT tail: LDS-staged MFMA partial DFT --------------
__device__ __forceinline__ void dft_phase(unsigned short* sh_hA, unsigned short* sh_ph,
                                          int tid, float* cPdst) {
    int wave = tid >> 6, lane = tid & 63;
    int quad = lane >> 4, frow = lane & 15;
    floatx4 acc00 = {0.f,0.f,0.f,0.f}, acc01 = {0.f,0.f,0.f,0.f};
    floatx4 acc10 = {0.f,0.f,0.f,0.f}, acc11 = {0.f,0.f,0.f,0.f};
    int kb = wave * 64 + quad * 8;
    #pragma unroll
    for (int kc = 0; kc < 2; ++kc) {
        int k = kb + kc * 32;
        short8 a0 = *(const short8*)(sh_hA + frow * RP + k);
        short8 a1 = *(const short8*)(sh_hA + (16 + frow) * RP + k);
        short8 bc = *(const short8*)(sh_ph + frow * RP + k);
        short8 bs = *(const short8*)(sh_ph + (16 + frow) * RP + k);
        acc00 = __builtin_amdgcn_mfma_f32_16x16x32_bf16(a0, bc, acc00, 0, 0, 0);
        acc01 = __builtin_amdgcn_mfma_f32_16x16x32_bf16(a0, bs, acc01, 0, 0, 0);
        acc10 = __builtin_amdgcn_mfma_f32_16x16x32_bf16(a1, bc, acc10, 0, 0, 0);
        acc11 = __builtin_amdgcn_mfma_f32_16x16x32_bf16(a1, bs, acc11, 0, 0, 0);
    }
    __syncthreads();
    float* red = (float*)sh_hA;
    #pragma unroll
    for (int r = 0; r < 4; ++r) {
        red[wave * 1024 + 0 * 256 + r * 64 + lane] = acc00[r];
        red[wave * 1024 + 1 * 256 + r * 64 + lane] = acc01[r];
        red[wave * 1024 + 2 * 256 + r * 64 + lane] = acc10[r];
        red[wave * 1024 + 3 * 256 + r * 64 + lane] = acc11[r];
    }
    __syncthreads();
    #pragma unroll
    for (int ii = 0; ii < 4; ++ii) {
        int idx = ii * 256 + tid;
        float v = red[idx] + red[1024 + idx] + red[2048 + idx] + red[3072 + idx];
        int f = idx >> 8;
        int r = (idx >> 6) & 3, ln = idx & 63;
        int o = (f >> 1) * 16 + (ln >> 4) * 4 + r;   // D row = quad*4+reg
        int m = ln & 15;                              // D col = lane&15
        if (o < CC) atomicAdd(cPdst + (f & 1) * 320 + o * 16 + m, v);
    }
}

// ---------------- k_fc0_dft: h2 (paired bf16 dwords) = fc0; DFT partials ----
__global__ __launch_bounds__(256, 4) void k_fc0_dft(const float* __restrict__ x,
        const float* __restrict__ pd, const float* __restrict__ w,
        const float* __restrict__ bias, const float* __restrict__ invmax,
        unsigned* __restrict__ h2, float* __restrict__ cP0) {
    __shared__ __align__(16) unsigned short sh_hA[32 * RP];
    __shared__ __align__(16) unsigned short sh_ph[32 * RP];
    int tid = threadIdx.x;
    {
        unsigned* z = (unsigned*)(sh_hA + CC * RP);
        for (int i = tid; i < (32 - CC) * RP / 2; i += 256) z[i] = 0;
    }
    int b = blockIdx.y;
    int s = blockIdx.x * 256 + tid;
    float xv = x[(size_t)b * SS + s];
    float g  = pd[s] * invmax[0];
    unsigned* hp2 = h2 + (size_t)b * (CC / 2) * SS + s;
    float u = (float)s * (1.0f / 32768.0f);
    float s1, c1; sincospif(u, &s1, &c1);
    float cm = 1.0f, sm = 0.0f;
    #pragma unroll
    for (int m = 0; m < NM; ++m) {
        sh_ph[m * RP + tid]        = f2bf(cm);
        sh_ph[(16 + m) * RP + tid] = f2bf(sm);
        float cn = cm * c1 - sm * s1;
        sm = sm * c1 + cm * s1;
        cm = cn;
    }
    #pragma unroll
    for (int p = 0; p < CC / 2; ++p) {
        int c0 = 2 * p, c1i = 2 * p + 1;
        float v0 = xv * w[c0]  + g * w[CC + c0]  + bias[c0];
        float v1 = xv * w[c1i] + g * w[CC + c1i] + bias[c1i];
        unsigned short a0 = f2bf(v0), a1 = f2bf(v1);
        hp2[(size_t)p * SS] = (unsigned)a0 | ((unsigned)a1 << 16);
        sh_hA[c0 * RP + tid]  = a0;
        sh_hA[c1i * RP + tid] = a1;
    }
    __syncthreads();
    dft_phase(sh_hA, sh_ph, tid, cP0 + ((size_t)(blockIdx.x & (NSLOT - 1)) * BB + b) * 640);
}

// ---------------- k_point_dft (layers 0..2): MFMA point-op + next-layer DFT -
// R19: SWAPPED MFMA operands — D[ch][s]: lane holds 4 CONSECUTIVE channels
// (quad*4+r) of one spatial col -> h2 dword pack is in-lane, zero shfl.
// Trig-lo term dropped (error ~1e-3, below bf16-h floor): 4 MFMA/tile,
// no ALO -> LDS 33792 B (AST 32K aliased by sh_hA/sh_ph 33.8K) -> 4 blocks/CU.
__global__ __launch_bounds__(256, 4) void k_point_dft(unsigned* __restrict__ h2,
        const unsigned short* __restrict__ Bpk,
        float* __restrict__ cPn) {
    __shared__ __align__(16) unsigned short LB[2 * 32 * RP];   // 33792 B
    unsigned short* AST   = LB;                  // 32 KB staged A-rows
    unsigned short* sh_hA = LB;                  // aliases, valid after barrier
    unsigned short* sh_ph = LB + 32 * RP;
    int tid = threadIdx.x;
    int b = blockIdx.y;
    int s = blockIdx.x * 256 + tid;

    // ---- phase A: trig + old-h load + A-row staging (wave-local) ------
    float u = (float)s * (1.0f / 32768.0f);
    float s1, c1; sincospif(u, &s1, &c1);
    float cm[NM], sm[NM];
    cm[0] = 1.0f; sm[0] = 0.0f;
    #pragma unroll
    for (int m = 1; m < NM; ++m) {
        cm[m] = cm[m - 1] * c1 - sm[m - 1] * s1;
        sm[m] = sm[m - 1] * c1 + cm[m - 1] * s1;
    }
    const unsigned* hp2r = h2 + (size_t)b * (CC / 2) * SS + s;
    unsigned hw[CC / 2];
    #pragma unroll
    for (int p = 0; p < CC / 2; ++p) hw[p] = hp2r[(size_t)p * SS];
    unsigned short chi[NM], shi[NM];
    #pragma unroll
    for (int m = 0; m < NM; ++m) { chi[m] = f2bf(cm[m]); shi[m] = f2bf(sm[m]); }
    stage_A(AST, tid, hw, chi, shi);
    // no barrier: phase B reads only this wave's rows, written by this wave

    // ---- phase B: MFMA point-op (swapped), gelu, in-lane pack, h2 -----
    int wave = tid >> 6, lane = tid & 63, col = lane & 15, quad = lane >> 4;
    const unsigned short* Bp = Bpk + (size_t)b * 4096;
    short8 wh0[2], wh1[2], wl0[2], wl1[2];
    #pragma unroll
    for (int cht = 0; cht < 2; ++cht) {
        int o = cht * 16 + col;
        wh0[cht] = *(const short8*)(Bp + o * 64 + quad * 8);
        wh1[cht] = *(const short8*)(Bp + o * 64 + 32 + quad * 8);
        wl0[cht] = *(const short8*)(Bp + 2048 + o * 64 + quad * 8);
        wl1[cht] = *(const short8*)(Bp + 2048 + o * 64 + 32 + quad * 8);
    }
    unsigned* h2b = h2 + (size_t)b * (CC / 2) * SS + blockIdx.x * 256;
    unsigned pkr[2][4][2];
    #pragma unroll
    for (int st = 0; st < 4; ++st) {
        int ar = wave * 64 + st * 16 + col;
        int sw = ar & 7;
        const unsigned short* abase = AST + ar * 64;
        short8 ah0 = *(const short8*)(abase + ((quad ^ sw) << 3));
        short8 ah1 = *(const short8*)(abase + (((4 + quad) ^ sw) << 3));
        #pragma unroll
        for (int cht = 0; cht < 2; ++cht) {
            floatx4 a = {0.f, 0.f, 0.f, 0.f};
            a = __builtin_amdgcn_mfma_f32_16x16x32_bf16(wh0[cht], ah0, a, 0, 0, 0);
            a = __builtin_amdgcn_mfma_f32_16x16x32_bf16(wh1[cht], ah1, a, 0, 0, 0);
            a = __builtin_amdgcn_mfma_f32_16x16x32_bf16(wl0[cht], ah0, a, 0, 0, 0);
            a = __builtin_amdgcn_mfma_f32_16x16x32_bf16(wl1[cht], ah1, a, 0, 0, 0);
            unsigned d0 = pk2(f2bf(gelu_fast(a[0])), f2bf(gelu_fast(a[1])));
            unsigned d1 = pk2(f2bf(gelu_fast(a[2])), f2bf(gelu_fast(a[3])));
            pkr[cht][st][0] = d0;
            pkr[cht][st][1] = d1;
            int p = cht * 8 + quad * 2;               // channel pair index
            if (p < CC / 2) {                          // cht1: quad0 only
                h2b[(size_t)p * SS + ar]       = d0;
                h2b[(size_t)(p + 1) * SS + ar] = d1;
            }
        }
    }
    __syncthreads();   // all waves' AST reads done; LDS becomes sh_hA/sh_ph

    // ---- phase C: scatter h_new to sh_hA, write sh_ph -----------------
    {
        unsigned* z = (unsigned*)(sh_hA + CC * RP);
        #pragma unroll
        for (int i = tid; i < (32 - CC) * RP / 2; i += 256) z[i] = 0;
    }
    #pragma unroll
    for (int m = 0; m < NM; ++m) {
        sh_ph[m * RP + tid]        = f2bf(cm[m]);
        sh_ph[(16 + m) * RP + tid] = f2bf(sm[m]);
    }
    #pragma unroll
    for (int cht = 0; cht < 2; ++cht) {
        int ob = cht * 16 + quad * 4;
        if (ob < CC) {
            #pragma unroll
            for (int st = 0; st < 4; ++st) {
                int s_loc = wave * 64 + st * 16 + col;
                #pragma unroll
                for (int rp = 0; rp < 2; ++rp) {
                    unsigned d = pkr[cht][st][rp];
                    sh_hA[(ob + 2 * rp) * RP + s_loc]     = (unsigned short)(d & 0xFFFFu);
                    sh_hA[(ob + 2 * rp + 1) * RP + s_loc] = (unsigned short)(d >> 16);
                }
            }
        }
    }
    __syncthreads();
    dft_phase(sh_hA, sh_ph, tid, cPn + ((size_t)(blockIdx.x & (NSLOT - 1)) * BB + b) * 640);
}

// ---------------- k_mix: partial reduce + complex mixing + B-panel pack -----
__global__ __launch_bounds__(320) void k_mix(const float* __restrict__ cP,
                                             const float* __restrict__ wre, const float* __restrict__ wim,
                                             const float* __restrict__ ww, const float* __restrict__ wb,
                                             float* __restrict__ cA, float* __restrict__ cB,
                                             unsigned short* __restrict__ Bpk) {
    int b = blockIdx.x, tid = threadIdx.x;
    __shared__ float PQ[640];
    const float* base = cP + (size_t)b * 640;
    int i = tid >> 4, m = tid & 15;
    float sP = 0.f, sQ = 0.f;
    #pragma unroll 4
    for (int sl = 0; sl < NSLOT; ++sl) {
        sP += base[(size_t)sl * BB * 640 + tid];
        sQ += base[(size_t)sl * BB * 640 + 320 + tid];
    }
    PQ[i * 32 + m]      = sP;
    PQ[i * 32 + 16 + m] = sQ;
    __syncthreads();
    int o = i;
    float reY = 0.f, imY = 0.f;
    #pragma unroll
    for (int c = 0; c < CC; ++c) {
        float P = PQ[c * 32 + m], Q = PQ[c * 32 + 16 + m];
        float wr = wre[(size_t)(c * CC + o) * NM + m];
        float wi = wim[(size_t)(c * CC + o) * NM + m];
        reY += P * wr + Q * wi;                // X = P - iQ
        imY += P * wi - Q * wr;
    }
    const float invS = 1.0f / (float)SS;
    float a, bb;
    if (m == 0) { a = reY * invS; bb = 0.0f; } // irfft drops Im(DC)
    else        { a = 2.0f * reY * invS; bb = -2.0f * imY * invS; }
    cA[(size_t)(b * CC + o) * NM + m] = a;
    cB[(size_t)(b * CC + o) * NM + m] = bb;

    // ---- pack B panels for the MFMA point-op (per-b) ------------------
    unsigned short* Bp = Bpk + (size_t)b * 4096;
    for (int idx = tid; idx < 640; idx += 320) {       // o<20, k 0..31
        int o8 = idx >> 5, k = idx & 31;
        float v = 0.f;
        if (k < CC) v = ww[o8 * CC + k];
        else if (k == CC) v = wb[o8];
        Bp[o8 * 64 + k]        = f2bf(v);
        Bp[2048 + o8 * 64 + k] = f2bflo(v);
    }
    for (int idx = tid; idx < 768; idx += 320) {       // o 20..31: zero rows
        int o8 = 20 + (idx >> 6), k = idx & 63;
        Bp[o8 * 64 + k] = 0;
        Bp[2048 + o8 * 64 + k] = 0;
    }
    Bp[o * 64 + 32 + m]        = f2bf(a);
    Bp[o * 64 + 48 + m]        = f2bf(bb);
    Bp[2048 + o * 64 + 32 + m] = f2bflo(a);
    Bp[2048 + o * 64 + 48 + m] = f2bflo(bb);
}

// ---------------- k_point_final: MFMA layer-3 point op + fc1 + gelu + fc2 ---
// R19: swapped-operand point-op -> in-lane hi/lo hT pack (zero shfl), no
// trig-lo -> LDS exactly 32768 B (5 blocks/CU). All LDS phases up to fc1 are
// wave-slice-local -> single barrier (before the cross-wave out read).
__global__ __launch_bounds__(256, 4) void k_point_final(const unsigned* __restrict__ h2,
        const unsigned short* __restrict__ Bpk,
        const unsigned short* __restrict__ w1Tg, const float* __restrict__ b1,
        const float* __restrict__ w2, const float* __restrict__ b2,
        float* __restrict__ out) {
    __shared__ __align__(16) unsigned short AST[256 * 64];   // 32768 B exactly
    unsigned short* hT = AST;            // aliased, wave-local throughout
    int tid = threadIdx.x;
    int b = blockIdx.y;
    int s = blockIdx.x * 256 + tid;

    // ---- phase A: trig + h load + A-row staging -----------------------
    float u = (float)s * (1.0f / 32768.0f);
    float s1, c1; sincospif(u, &s1, &c1);
    float cm[NM], sm[NM];
    cm[0] = 1.0f; sm[0] = 0.0f;
    #pragma unroll
    for (int m = 1; m < NM; ++m) {
        cm[m] = cm[m - 1] * c1 - sm[m - 1] * s1;
        sm[m] = sm[m - 1] * c1 + cm[m - 1] * s1;
    }
    const unsigned* hp2r = h2 + (size_t)b * (CC / 2) * SS + s;
    unsigned hw[CC / 2];
    #pragma unroll
    for (int p = 0; p < CC / 2; ++p) hw[p] = hp2r[(size_t)p * SS];
    unsigned short chi[NM], shi[NM];
    #pragma unroll
    for (int m = 0; m < NM; ++m) { chi[m] = f2bf(cm[m]); shi[m] = f2bf(sm[m]); }
    stage_A(AST, tid, hw, chi, shi);
    // no barrier: wave-local

    // ---- phase B: point-op MFMA (swapped, no gelu) --------------------
    int wave = tid >> 6, lane = tid & 63, col = lane & 15, quad = lane >> 4;
    const unsigned short* Bp = Bpk + (size_t)b * 4096;
    short8 wh0[2], wh1[2], wl0[2], wl1[2];
    #pragma unroll
    for (int cht = 0; cht < 2; ++cht) {
        int o = cht * 16 + col;
        wh0[cht] = *(const short8*)(Bp + o * 64 + quad * 8);
        wh1[cht] = *(const short8*)(Bp + o * 64 + 32 + quad * 8);
        wl0[cht] = *(const short8*)(Bp + 2048 + o * 64 + quad * 8);
        wl1[cht] = *(const short8*)(Bp + 2048 + o * 64 + 32 + quad * 8);
    }
    float res[2][4][4];   // [cht][st][r] — statically indexed
    #pragma unroll
    for (int st = 0; st < 4; ++st) {
        int ar = wave * 64 + st * 16 + col;
        int sw = ar & 7;
        const unsigned short* abase = AST + ar * 64;
        short8 ah0 = *(const short8*)(abase + ((quad ^ sw) << 3));
        short8 ah1 = *(const short8*)(abase + (((4 + quad) ^ sw) << 3));
        #pragma unroll
        for (int cht = 0; cht < 2; ++cht) {
            floatx4 a = {0.f, 0.f, 0.f, 0.f};
            a = __builtin_amdgcn_mfma_f32_16x16x32_bf16(wh0[cht], ah0, a, 0, 0, 0);
            a = __builtin_amdgcn_mfma_f32_16x16x32_bf16(wh1[cht], ah1, a, 0, 0, 0);
            a = __builtin_amdgcn_mfma_f32_16x16x32_bf16(wl0[cht], ah0, a, 0, 0, 0);
            a = __builtin_amdgcn_mfma_f32_16x16x32_bf16(wl1[cht], ah1, a, 0, 0, 0);
            #pragma unroll
            for (int r = 0; r < 4; ++r) res[cht][st][r] = a[r];
        }
    }
    // no barrier: phase C writes this wave's own rows only

    // ---- phase C: in-lane hi/lo pack into hT (dead AST rows) ----------
    #pragma unroll
    for (int cht = 0; cht < 2; ++cht) {
        #pragma unroll
        for (int st = 0; st < 4; ++st) {
            int row = wave * 64 + st * 16 + col;
            int sw = row & 7;
            unsigned* rb = (unsigned*)(hT + row * WP);
            #pragma unroll
            for (int rp = 0; rp < 2; ++rp) {
                int dwi = cht * 8 + quad * 2 + rp;
                if (dwi < CC / 2) {                    // cht1: quad0 only
                    float f0 = res[cht][st][2 * rp], f1 = res[cht][st][2 * rp + 1];
                    unsigned short h0 = f2bf(f0), h1 = f2bf(f1);
                    unsigned short l0 = f2bf(f0 - bf2f(h0)), l1 = f2bf(f1 - bf2f(h1));
                    int chunk = dwi >> 2, pos = dwi & 3;
                    rb[((chunk ^ sw) << 2) + pos]       = pk2(h0, h1);
                    rb[(((chunk + 4) ^ sw) << 2) + pos] = pk2(l0, l1);
                }
            }
        }
    }
    // no barrier: fc1 reads this wave's own rows only

    // ---- fc1 MFMA + gelu + fc2 ----------------------------------------
    short8 bhi[8], blo[8];
    #pragma unroll
    for (int nt = 0; nt < 8; ++nt) {
        bhi[nt] = *(const short8*)(w1Tg + (size_t)(nt * 16 + col) * 64 + quad * 8);
        blo[nt] = *(const short8*)(w1Tg + (size_t)(nt * 16 + col) * 64 + 32 + quad * 8);
    }
    float lb1r[8], w2r[8];
    #pragma unroll
    for (int nt = 0; nt < 8; ++nt) { lb1r[nt] = b1[nt * 16 + col]; w2r[nt] = w2[nt * 16 + col]; }
    float b2v = b2[0];
    #pragma unroll
    for (int mt = 0; mt < 4; ++mt) {
        int srow = wave * 64 + mt * 16 + col;     // A row m = lane&15
        int sw = srow & 7;
        short8 ahi = *(const short8*)(hT + srow * WP + ((quad ^ sw) << 3));
        short8 alo = *(const short8*)(hT + srow * WP + (((quad ^ sw) ^ 4) << 3));
        float part[4] = {0.f, 0.f, 0.f, 0.f};
        #pragma unroll
        for (int nt = 0; nt < 8; ++nt) {
            floatx4 a = {0.f, 0.f, 0.f, 0.f};
            a = __builtin_amdgcn_mfma_f32_16x16x32_bf16(ahi, bhi[nt], a, 0, 0, 0);
            a = __builtin_amdgcn_mfma_f32_16x16x32_bf16(ahi, blo[nt], a, 0, 0, 0);
            a = __builtin_amdgcn_mfma_f32_16x16x32_bf16(alo, bhi[nt], a, 0, 0, 0);
            #pragma unroll
            for (int r = 0; r < 4; ++r) {
                float t = gelu_fast(a[r] + lb1r[nt]);
                part[r] += t * w2r[nt];
            }
        }
        #pragma unroll
        for (int r = 0; r < 4; ++r) {
            float p = part[r];
            p += __shfl_xor(p, 1, 64);
            p += __shfl_xor(p, 2, 64);
            p += __shfl_xor(p, 4, 64);
            p += __shfl_xor(p, 8, 64);
            if (col == 0) {
                int row = wave * 64 + mt * 16 + quad * 4 + r;   // dead rows of this tile
                *(float*)(&hT[row * WP + ((row & 7) << 3)]) = p + b2v;
            }
        }
    }
    __syncthreads();      // the single cross-wave hand-off
    out[(size_t)b * SS + blockIdx.x * 256 + tid] = *(const float*)(&hT[tid * WP + ((tid & 7) << 3)]);
}

extern "C" void kernel_launch(void* const* d_in, const int* in_sizes, int n_in,
                              void* d_out, int out_size, void* d_ws, size_t ws_size,
                              hipStream_t stream) {
    (void)in_sizes; (void)n_in; (void)out_size; (void)ws_size;
    const float* x    = (const float*)d_in[0];
    const float* pd   = (const float*)d_in[1];
    const float* fc0w = (const float*)d_in[2];
    const float* fc0b = (const float*)d_in[3];
    const float* fc1w = (const float*)d_in[4];
    const float* fc1b = (const float*)d_in[5];
    const float* fc2w = (const float*)d_in[6];
    const float* fc2b = (const float*)d_in[7];

    char* ws = (char*)d_ws;
    unsigned* h2 = (unsigned*)ws;
    size_t off = (size_t)BB * (CC / 2) * SS * 4;                      // 83.9 MB (paired bf16)
    float* cP = (float*)(ws + off); off += (size_t)4 * NSLOT * BB * 640 * 4;  // 5.24 MB
    float* cA = (float*)(ws + off); off += (size_t)BB * CC * NM * 4;
    float* cB = (float*)(ws + off); off += (size_t)BB * CC * NM * 4;
    float* invmax = (float*)(ws + off); off += 256;
    unsigned short* w1Tg = (unsigned short*)(ws + off); off += (size_t)HH * 64 * 2;  // 16 KB
    unsigned short* Bpk  = (unsigned short*)(ws + off); off += (size_t)BB * 4096 * 2; // 256 KB
    const size_t CPL = (size_t)NSLOT * BB * 640;   // floats per layer-slot set

    dim3 gBS(SS / 256, BB);

    k_prep<<<1282, 256, 0, stream>>>(pd, fc1w, invmax, cP, w1Tg);
    k_fc0_dft<<<gBS, 256, 0, stream>>>(x, pd, fc0w, fc0b, invmax, h2, cP);

    for (int l = 0; l < 3; ++l) {
        const float* wre = (const float*)d_in[8 + 4 * l];
        const float* wim = (const float*)d_in[9 + 4 * l];
        const float* ww  = (const float*)d_in[10 + 4 * l];
        const float* wb  = (const float*)d_in[11 + 4 * l];
        k_mix<<<BB, 320, 0, stream>>>(cP + (size_t)l * CPL, wre, wim, ww, wb, cA, cB, Bpk);
        k_point_dft<<<gBS, 256, 0, stream>>>(h2, Bpk, cP + (size_t)(l + 1) * CPL);
    }
    {   // layer 3 fused with fc1/gelu/fc2
        const float* wre = (const float*)d_in[20];
        const float* wim = (const float*)d_in[21];
        const float* ww  = (const float*)d_in[22];
        const float* wb  = (const float*)d_in[23];
        k_mix<<<BB, 320, 0, stream>>>(cP + (size_t)3 * CPL, wre, wim, ww, wb, cA, cB, Bpk);
        k_point_final<<<gBS, 256, 0, stream>>>(h2, Bpk,
                                               w1Tg, fc1b, fc2w, fc2b, (float*)d_out);
    }
}

// Round 6
// 531.755 us; speedup vs baseline: 1.3136x; 1.0320x over previous
//
#include <hip/hip_runtime.h>
#include <math.h>

#define BB 32
#define SS 65536
#define CC 20
#define NM 16
#define HH 128
#define RP 264   // DFT LDS row pitch (bf16 elems)
#define WP 64    // hT row pitch (bf16 elems): 8x short8 payload, XOR-swizzled chunks
#define NSLOT 16

using short8  = __attribute__((ext_vector_type(8))) short;
using floatx4 = __attribute__((ext_vector_type(4))) float;

__device__ __forceinline__ unsigned short f2bf(float f) {
    union { float f; unsigned u; } v; v.f = f;
    unsigned u = v.u;
    return (unsigned short)((u + 0x7FFFu + ((u >> 16) & 1u)) >> 16);   // RNE
}
__device__ __forceinline__ float bf2f(unsigned short h) {
    union { unsigned u; float f; } v; v.u = ((unsigned)h) << 16; return v.f;
}
__device__ __forceinline__ unsigned short f2bflo(float a) {
    return f2bf(a - bf2f(f2bf(a)));
}
__device__ __forceinline__ unsigned pk2(unsigned short lo, unsigned short hi) {
    return (unsigned)lo | ((unsigned)hi << 16);
}

// Tanh-form gelu, native exp2/rcp (R11). |delta| vs erf-gelu ~3e-4.
__device__ __forceinline__ float gelu_fast(float v) {
    float u = v * v;
    float inner = v * fmaf(0.0356774081f, u, 0.7978845608f);
    float e = __builtin_amdgcn_exp2f(inner * 2.8853900818f);
    float r = __builtin_amdgcn_rcpf(e + 1.0f);
    return fmaf(-v, r, v);
}

// R20: exact 16-lane (DPP-row) sum via rotation reduce — replaces 4x shfl_xor
// (ds_swizzle, LDS pipe) with VALU mov_dpp+add. row_ror:n = 0x120|n.
__device__ __forceinline__ float row16_sum(float p) {
    union { float f; int i; } v, w;
    v.f = p;
    w.i = __builtin_amdgcn_update_dpp(0, v.i, 0x121, 0xF, 0xF, true); v.f += w.f;
    w.i = __builtin_amdgcn_update_dpp(0, v.i, 0x122, 0xF, 0xF, true); v.f += w.f;
    w.i = __builtin_amdgcn_update_dpp(0, v.i, 0x124, 0xF, 0xF, true); v.f += w.f;
    w.i = __builtin_amdgcn_update_dpp(0, v.i, 0x128, 0xF, 0xF, true); v.f += w.f;
    return v.f;
}

// R19/R20: shared A-row staging — [h(20)|1|pad(11)|cm_hi(16)|sm_hi(16)],
// XOR-chunk swizzled. Chunks 4..7 come straight from the trig table row.
__device__ __forceinline__ void stage_A(unsigned short* AST, int tid,
                                        const unsigned* hw,
                                        uint4 tc0, uint4 tc1, uint4 ts0, uint4 ts1) {
    int sw = tid & 7;
    unsigned* base = (unsigned*)(AST + tid * 64);
    *(uint4*)(base + ((0 ^ sw) << 2)) = (uint4){hw[0], hw[1], hw[2], hw[3]};
    *(uint4*)(base + ((1 ^ sw) << 2)) = (uint4){hw[4], hw[5], hw[6], hw[7]};
    *(uint4*)(base + ((2 ^ sw) << 2)) = (uint4){hw[8], hw[9], 0x00003F80u, 0u};  // h16..19, ONE, 0
    *(uint4*)(base + ((3 ^ sw) << 2)) = (uint4){0u, 0u, 0u, 0u};
    *(uint4*)(base + ((4 ^ sw) << 2)) = tc0;
    *(uint4*)(base + ((5 ^ sw) << 2)) = tc1;
    *(uint4*)(base + ((6 ^ sw) << 2)) = ts0;
    *(uint4*)(base + ((7 ^ sw) << 2)) = ts1;
}

// ---------------- k_prep: max-reduce + zero cP + w1T + trig table ----------
// R20: w1Tg rows 20/52 carry fc1 bias hi/lo (b1 folded into the fc1 MFMA via
// hT's ONE slot). Blocks 1282..1537 build the global bf16 trig table
// (65536 rows x 64B: [cm pairs | sm pairs] — exactly stage_A chunks 4..7).
__global__ __launch_bounds__(256) void k_prep(const float* __restrict__ pd,
                                              const float* __restrict__ w1,
                                              const float* __restrict__ b1f,
                                              float* __restrict__ invmax,
                                              float* __restrict__ cP,
                                              unsigned short* __restrict__ w1Tg,
                                              unsigned* __restrict__ trigT) {
    int bx = blockIdx.x;
    if (bx == 0) {
        __shared__ float red[256];
        int t = threadIdx.x;
        float m = -1e30f;
        for (int i = t; i < SS; i += 256) m = fmaxf(m, pd[i]);
        red[t] = m; __syncthreads();
        for (int off = 128; off > 0; off >>= 1) {
            if (t < off) red[t] = fmaxf(red[t], red[t + off]);
            __syncthreads();
        }
        if (t == 0) invmax[0] = 1.0f / red[0];
    } else if (bx <= 1280) {
        int idx = (bx - 1) * 256 + threadIdx.x;   // 1280*256 float4 = 4*16*32*640 floats
        float4 z = {0.f, 0.f, 0.f, 0.f};
        ((float4*)cP)[idx] = z;
    } else if (bx == 1281) {
        for (int idx = threadIdx.x; idx < HH * 64; idx += 256) {
            int j = idx >> 6, k = idx & 63;
            unsigned short r = 0;
            if (k < CC) r = f2bf(w1[k * HH + j]);
            else if (k == CC) r = f2bf(b1f[j]);
            else if (k >= 32 && k < 32 + CC) r = f2bflo(w1[(k - 32) * HH + j]);
            else if (k == 32 + CC) r = f2bflo(b1f[j]);
            w1Tg[idx] = r;
        }
    } else {   // bx in [1282, 1537]: trig table
        int s = (bx - 1282) * 256 + threadIdx.x;
        float u = (float)s * (1.0f / 32768.0f);
        float s1, c1; sincospif(u, &s1, &c1);
        float cm = 1.0f, sm = 0.0f;
        unsigned short ch[NM], sh[NM];
        #pragma unroll
        for (int m = 0; m < NM; ++m) {
            ch[m] = f2bf(cm); sh[m] = f2bf(sm);
            float cn = cm * c1 - sm * s1;
            sm = sm * c1 + cm * s1;
            cm = cn;
        }
        uint4* row = (uint4*)(trigT + (size_t)s * 16);
        row[0] = (uint4){pk2(ch[0],ch[1]), pk2(ch[2],ch[3]), pk2(ch[4],ch[5]), pk2(ch[6],ch[7])};
        row[1] = (uint4){pk2(ch[8],ch[9]), pk2(ch[10],ch[11]), pk2(ch[12],ch[13]), pk2(ch[14],ch[15])};
        row[2] = (uint4){pk2(sh[0],sh[1]), pk2(sh[2],sh[3]), pk2(sh[4],sh[5]), pk2(sh[6],sh[7])};
        row[3] = (uint4){pk2(sh[8],sh[9]), pk2(sh[10],sh[11]), pk2(sh[12],sh[13]), pk2(sh[14],sh[15])};
    }
}

// ---------------- shared DFT tail: LDS-staged MFMA partial DFT --------------
__device__ __forceinline__ void dft_phase(unsigned short* sh_hA, unsigned short* sh_ph,
                                          int tid, float* cPdst) {
    int wave = tid >> 6, lane = tid & 63;
    int quad = lane >> 4, frow = lane & 15;
    floatx4 acc00 = {0.f,0.f,0.f,0.f}, acc01 = {0.f,0.f,0.f,0.f};
    floatx4 acc10 = {0.f,0.f,0.f,0.f}, acc11 = {0.f,0.f,0.f,0.f};
    int kb = wave * 64 + quad * 8;
    #pragma unroll
    for (int kc = 0; kc < 2; ++kc) {
        int k = kb + kc * 32;
        short8 a0 = *(const short8*)(sh_hA + frow * RP + k);
        short8 a1 = *(const short8*)(sh_hA + (16 + frow) * RP + k);
        short8 bc = *(const short8*)(sh_ph + frow * RP + k);
        short8 bs = *(const short8*)(sh_ph + (16 + frow) * RP + k);
        acc00 = __builtin_amdgcn_mfma_f32_16x16x32_bf16(a0, bc, acc00, 0, 0, 0);
        acc01 = __builtin_amdgcn_mfma_f32_16x16x32_bf16(a0, bs, acc01, 0, 0, 0);
        acc10 = __builtin_amdgcn_mfma_f32_16x16x32_bf16(a1, bc, acc10, 0, 0, 0);
        acc11 = __builtin_amdgcn_mfma_f32_16x16x32_bf16(a1, bs, acc11, 0, 0, 0);
    }
    __syncthreads();
    float* red = (float*)sh_hA;
    #pragma unroll
    for (int r = 0; r < 4; ++r) {
        red[wave * 1024 + 0 * 256 + r * 64 + lane] = acc00[r];
        red[wave * 1024 + 1 * 256 + r * 64 + lane] = acc01[r];
        red[wave * 1024 + 2 * 256 + r * 64 + lane] = acc10[r];
        red[wave * 1024 + 3 * 256 + r * 64 + lane] = acc11[r];
    }
    __syncthreads();
    #pragma unroll
    for (int ii = 0; ii < 4; ++ii) {
        int idx = ii * 256 + tid;
        float v = red[idx] + red[1024 + idx] + red[2048 + idx] + red[3072 + idx];
        int f = idx >> 8;
        int r = (idx >> 6) & 3, ln = idx & 63;
        int o = (f >> 1) * 16 + (ln >> 4) * 4 + r;   // D row = quad*4+reg
        int m = ln & 15;                              // D col = lane&15
        if (o < CC) atomicAdd(cPdst + (f & 1) * 320 + o * 16 + m, v);
    }
}

// ---------------- k_fc0_dft: h2 (paired bf16 dwords) = fc0; DFT partials ----
// R20: sh_ph from the global trig table (4x b128 load + bit extracts) — no
// per-thread sincospif/recurrence/f2bf.
__global__ __launch_bounds__(256, 4) void k_fc0_dft(const float* __restrict__ x,
        const float* __restrict__ pd, const float* __restrict__ w,
        const float* __restrict__ bias, const float* __restrict__ invmax,
        const unsigned* __restrict__ trigT,
        unsigned* __restrict__ h2, float* __restrict__ cP0) {
    __shared__ __align__(16) unsigned short sh_hA[32 * RP];
    __shared__ __align__(16) unsigned short sh_ph[32 * RP];
    int tid = threadIdx.x;
    {
        unsigned* z = (unsigned*)(sh_hA + CC * RP);
        for (int i = tid; i < (32 - CC) * RP / 2; i += 256) z[i] = 0;
    }
    int b = blockIdx.y;
    int s = blockIdx.x * 256 + tid;
    float xv = x[(size_t)b * SS + s];
    float g  = pd[s] * invmax[0];
    unsigned* hp2 = h2 + (size_t)b * (CC / 2) * SS + s;
    const uint4* trow = (const uint4*)(trigT + (size_t)s * 16);
    uint4 tc0 = trow[0], tc1 = trow[1], ts0 = trow[2], ts1 = trow[3];
    unsigned c8[8] = {tc0.x, tc0.y, tc0.z, tc0.w, tc1.x, tc1.y, tc1.z, tc1.w};
    unsigned s8[8] = {ts0.x, ts0.y, ts0.z, ts0.w, ts1.x, ts1.y, ts1.z, ts1.w};
    #pragma unroll
    for (int m = 0; m < NM; ++m) {
        unsigned cd = c8[m >> 1], sd = s8[m >> 1];
        sh_ph[m * RP + tid]        = (unsigned short)((m & 1) ? (cd >> 16) : (cd & 0xFFFFu));
        sh_ph[(16 + m) * RP + tid] = (unsigned short)((m & 1) ? (sd >> 16) : (sd & 0xFFFFu));
    }
    #pragma unroll
    for (int p = 0; p < CC / 2; ++p) {
        int c0 = 2 * p, c1i = 2 * p + 1;
        float v0 = xv * w[c0]  + g * w[CC + c0]  + bias[c0];
        float v1 = xv * w[c1i] + g * w[CC + c1i] + bias[c1i];
        unsigned short a0 = f2bf(v0), a1 = f2bf(v1);
        hp2[(size_t)p * SS] = (unsigned)a0 | ((unsigned)a1 << 16);
        sh_hA[c0 * RP + tid]  = a0;
        sh_hA[c1i * RP + tid] = a1;
    }
    __syncthreads();
    dft_phase(sh_hA, sh_ph, tid, cP0 + ((size_t)(blockIdx.x & (NSLOT - 1)) * BB + b) * 640);
}

// ---------------- k_point_dft (layers 0..2): MFMA point-op + next-layer DFT -
// R19 structure + R20 trig table. 4 blocks/CU.
__global__ __launch_bounds__(256, 4) void k_point_dft(unsigned* __restrict__ h2,
        const unsigned short* __restrict__ Bpk,
        const unsigned* __restrict__ trigT,
        float* __restrict__ cPn) {
    __shared__ __align__(16) unsigned short LB[2 * 32 * RP];   // 33792 B
    unsigned short* AST   = LB;                  // 32 KB staged A-rows
    unsigned short* sh_hA = LB;                  // aliases, valid after barrier
    unsigned short* sh_ph = LB + 32 * RP;
    int tid = threadIdx.x;
    int b = blockIdx.y;
    int s = blockIdx.x * 256 + tid;

    // ---- phase A: table load + old-h load + A-row staging (wave-local) ----
    const uint4* trow = (const uint4*)(trigT + (size_t)s * 16);
    uint4 tc0 = trow[0], tc1 = trow[1], ts0 = trow[2], ts1 = trow[3];
    const unsigned* hp2r = h2 + (size_t)b * (CC / 2) * SS + s;
    unsigned hw[CC / 2];
    #pragma unroll
    for (int p = 0; p < CC / 2; ++p) hw[p] = hp2r[(size_t)p * SS];
    stage_A(AST, tid, hw, tc0, tc1, ts0, ts1);
    // no barrier: phase B reads only this wave's rows, written by this wave

    // ---- phase B: MFMA point-op (swapped), gelu, in-lane pack, h2 -----
    int wave = tid >> 6, lane = tid & 63, col = lane & 15, quad = lane >> 4;
    const unsigned short* Bp = Bpk + (size_t)b * 4096;
    short8 wh0[2], wh1[2], wl0[2], wl1[2];
    #pragma unroll
    for (int cht = 0; cht < 2; ++cht) {
        int o = cht * 16 + col;
        wh0[cht] = *(const short8*)(Bp + o * 64 + quad * 8);
        wh1[cht] = *(const short8*)(Bp + o * 64 + 32 + quad * 8);
        wl0[cht] = *(const short8*)(Bp + 2048 + o * 64 + quad * 8);
        wl1[cht] = *(const short8*)(Bp + 2048 + o * 64 + 32 + quad * 8);
    }
    unsigned* h2b = h2 + (size_t)b * (CC / 2) * SS + blockIdx.x * 256;
    unsigned pkr[2][4][2];
    #pragma unroll
    for (int st = 0; st < 4; ++st) {
        int ar = wave * 64 + st * 16 + col;
        int sw = ar & 7;
        const unsigned short* abase = AST + ar * 64;
        short8 ah0 = *(const short8*)(abase + ((quad ^ sw) << 3));
        short8 ah1 = *(const short8*)(abase + (((4 + quad) ^ sw) << 3));
        #pragma unroll
        for (int cht = 0; cht < 2; ++cht) {
            floatx4 a = {0.f, 0.f, 0.f, 0.f};
            a = __builtin_amdgcn_mfma_f32_16x16x32_bf16(wh0[cht], ah0, a, 0, 0, 0);
            a = __builtin_amdgcn_mfma_f32_16x16x32_bf16(wh1[cht], ah1, a, 0, 0, 0);
            a = __builtin_amdgcn_mfma_f32_16x16x32_bf16(wl0[cht], ah0, a, 0, 0, 0);
            a = __builtin_amdgcn_mfma_f32_16x16x32_bf16(wl1[cht], ah1, a, 0, 0, 0);
            unsigned d0 = pk2(f2bf(gelu_fast(a[0])), f2bf(gelu_fast(a[1])));
            unsigned d1 = pk2(f2bf(gelu_fast(a[2])), f2bf(gelu_fast(a[3])));
            pkr[cht][st][0] = d0;
            pkr[cht][st][1] = d1;
            int p = cht * 8 + quad * 2;               // channel pair index
            if (p < CC / 2) {                          // cht1: quad0 only
                h2b[(size_t)p * SS + ar]       = d0;
                h2b[(size_t)(p + 1) * SS + ar] = d1;
            }
        }
    }
    __syncthreads();   // all waves' AST reads done; LDS becomes sh_hA/sh_ph

    // ---- phase C: scatter h_new to sh_hA, write sh_ph from table ------
    {
        unsigned* z = (unsigned*)(sh_hA + CC * RP);
        #pragma unroll
        for (int i = tid; i < (32 - CC) * RP / 2; i += 256) z[i] = 0;
    }
    {
        unsigned c8[8] = {tc0.x, tc0.y, tc0.z, tc0.w, tc1.x, tc1.y, tc1.z, tc1.w};
        unsigned s8[8] = {ts0.x, ts0.y, ts0.z, ts0.w, ts1.x, ts1.y, ts1.z, ts1.w};
        #pragma unroll
        for (int m = 0; m < NM; ++m) {
            unsigned cd = c8[m >> 1], sd = s8[m >> 1];
            sh_ph[m * RP + tid]        = (unsigned short)((m & 1) ? (cd >> 16) : (cd & 0xFFFFu));
            sh_ph[(16 + m) * RP + tid] = (unsigned short)((m & 1) ? (sd >> 16) : (sd & 0xFFFFu));
        }
    }
    #pragma unroll
    for (int cht = 0; cht < 2; ++cht) {
        int ob = cht * 16 + quad * 4;
        if (ob < CC) {
            #pragma unroll
            for (int st = 0; st < 4; ++st) {
                int s_loc = wave * 64 + st * 16 + col;
                #pragma unroll
                for (int rp = 0; rp < 2; ++rp) {
                    unsigned d = pkr[cht][st][rp];
                    sh_hA[(ob + 2 * rp) * RP + s_loc]     = (unsigned short)(d & 0xFFFFu);
                    sh_hA[(ob + 2 * rp + 1) * RP + s_loc] = (unsigned short)(d >> 16);
                }
            }
        }
    }
    __syncthreads();
    dft_phase(sh_hA, sh_ph, tid, cPn + ((size_t)(blockIdx.x & (NSLOT - 1)) * BB + b) * 640);
}

// ---------------- k_mix: partial reduce + complex mixing + B-panel pack -----
__global__ __launch_bounds__(320) void k_mix(const float* __restrict__ cP,
                                             const float* __restrict__ wre, const float* __restrict__ wim,
                                             const float* __restrict__ ww, const float* __restrict__ wb,
                                             float* __restrict__ cA, float* __restrict__ cB,
                                             unsigned short* __restrict__ Bpk) {
    int b = blockIdx.x, tid = threadIdx.x;
    __shared__ float PQ[640];
    const float* base = cP + (size_t)b * 640;
    int i = tid >> 4, m = tid & 15;
    float sP = 0.f, sQ = 0.f;
    #pragma unroll 4
    for (int sl = 0; sl < NSLOT; ++sl) {
        sP += base[(size_t)sl * BB * 640 + tid];
        sQ += base[(size_t)sl * BB * 640 + 320 + tid];
    }
    PQ[i * 32 + m]      = sP;
    PQ[i * 32 + 16 + m] = sQ;
    __syncthreads();
    int o = i;
    float reY = 0.f, imY = 0.f;
    #pragma unroll
    for (int c = 0; c < CC; ++c) {
        float P = PQ[c * 32 + m], Q = PQ[c * 32 + 16 + m];
        float wr = wre[(size_t)(c * CC + o) * NM + m];
        float wi = wim[(size_t)(c * CC + o) * NM + m];
        reY += P * wr + Q * wi;                // X = P - iQ
        imY += P * wi - Q * wr;
    }
    const float invS = 1.0f / (float)SS;
    float a, bb;
    if (m == 0) { a = reY * invS; bb = 0.0f; } // irfft drops Im(DC)
    else        { a = 2.0f * reY * invS; bb = -2.0f * imY * invS; }
    cA[(size_t)(b * CC + o) * NM + m] = a;
    cB[(size_t)(b * CC + o) * NM + m] = bb;

    // ---- pack B panels for the MFMA point-op (per-b) ------------------
    unsigned short* Bp = Bpk + (size_t)b * 4096;
    for (int idx = tid; idx < 640; idx += 320) {       // o<20, k 0..31
        int o8 = idx >> 5, k = idx & 31;
        float v = 0.f;
        if (k < CC) v = ww[o8 * CC + k];
        else if (k == CC) v = wb[o8];
        Bp[o8 * 64 + k]        = f2bf(v);
        Bp[2048 + o8 * 64 + k] = f2bflo(v);
    }
    for (int idx = tid; idx < 768; idx += 320) {       // o 20..31: zero rows
        int o8 = 20 + (idx >> 6), k = idx & 63;
        Bp[o8 * 64 + k] = 0;
        Bp[2048 + o8 * 64 + k] = 0;
    }
    Bp[o * 64 + 32 + m]        = f2bf(a);
    Bp[o * 64 + 48 + m]        = f2bf(bb);
    Bp[2048 + o * 64 + 32 + m] = f2bflo(a);
    Bp[2048 + o * 64 + 48 + m] = f2bflo(bb);
}

// ---------------- k_point_final: MFMA layer-3 point op + fc1 + gelu + fc2 ---
// R19 structure + R20: trig table; b1 folded into w1Tg rows 20/52 via hT's
// ONE slot (dwi==10); DPP rotation reduce for fc2. LDS 32768 B.
__global__ __launch_bounds__(256, 4) void k_point_final(const unsigned* __restrict__ h2,
        const unsigned short* __restrict__ Bpk,
        const unsigned short* __restrict__ w1Tg,
        const float* __restrict__ w2, const float* __restrict__ b2,
        const unsigned* __restrict__ trigT,
        float* __restrict__ out) {
    __shared__ __align__(16) unsigned short AST[256 * 64];   // 32768 B exactly
    unsigned short* hT = AST;            // aliased, wave-local throughout
    int tid = threadIdx.x;
    int b = blockIdx.y;
    int s = blockIdx.x * 256 + tid;

    // ---- phase A: table load + h load + A-row staging -----------------
    const uint4* trow = (const uint4*)(trigT + (size_t)s * 16);
    uint4 tc0 = trow[0], tc1 = trow[1], ts0 = trow[2], ts1 = trow[3];
    const unsigned* hp2r = h2 + (size_t)b * (CC / 2) * SS + s;
    unsigned hw[CC / 2];
    #pragma unroll
    for (int p = 0; p < CC / 2; ++p) hw[p] = hp2r[(size_t)p * SS];
    stage_A(AST, tid, hw, tc0, tc1, ts0, ts1);
    // no barrier: wave-local

    // ---- phase B: point-op MFMA (swapped, no gelu) --------------------
    int wave = tid >> 6, lane = tid & 63, col = lane & 15, quad = lane >> 4;
    const unsigned short* Bp = Bpk + (size_t)b * 4096;
    short8 wh0[2], wh1[2], wl0[2], wl1[2];
    #pragma unroll
    for (int cht = 0; cht < 2; ++cht) {
        int o = cht * 16 + col;
        wh0[cht] = *(const short8*)(Bp + o * 64 + quad * 8);
        wh1[cht] = *(const short8*)(Bp + o * 64 + 32 + quad * 8);
        wl0[cht] = *(const short8*)(Bp + 2048 + o * 64 + quad * 8);
        wl1[cht] = *(const short8*)(Bp + 2048 + o * 64 + 32 + quad * 8);
    }
    float res[2][4][4];   // [cht][st][r] — statically indexed
    #pragma unroll
    for (int st = 0; st < 4; ++st) {
        int ar = wave * 64 + st * 16 + col;
        int sw = ar & 7;
        const unsigned short* abase = AST + ar * 64;
        short8 ah0 = *(const short8*)(abase + ((quad ^ sw) << 3));
        short8 ah1 = *(const short8*)(abase + (((4 + quad) ^ sw) << 3));
        #pragma unroll
        for (int cht = 0; cht < 2; ++cht) {
            floatx4 a = {0.f, 0.f, 0.f, 0.f};
            a = __builtin_amdgcn_mfma_f32_16x16x32_bf16(wh0[cht], ah0, a, 0, 0, 0);
            a = __builtin_amdgcn_mfma_f32_16x16x32_bf16(wh1[cht], ah1, a, 0, 0, 0);
            a = __builtin_amdgcn_mfma_f32_16x16x32_bf16(wl0[cht], ah0, a, 0, 0, 0);
            a = __builtin_amdgcn_mfma_f32_16x16x32_bf16(wl1[cht], ah1, a, 0, 0, 0);
            #pragma unroll
            for (int r = 0; r < 4; ++r) res[cht][st][r] = a[r];
        }
    }
    // no barrier: phase C writes this wave's own rows only

    // ---- phase C: in-lane hi/lo pack into hT; dwi==10 = (ONE,0) bias slot --
    #pragma unroll
    for (int cht = 0; cht < 2; ++cht) {
        #pragma unroll
        for (int st = 0; st < 4; ++st) {
            int row = wave * 64 + st * 16 + col;
            int sw = row & 7;
            unsigned* rb = (unsigned*)(hT + row * WP);
            #pragma unroll
            for (int rp = 0; rp < 2; ++rp) {
                int dwi = cht * 8 + quad * 2 + rp;
                if (dwi <= CC / 2) {                   // 10 = bias ONE slot
                    float f0, f1;
                    if (dwi == CC / 2) { f0 = 1.0f; f1 = 0.0f; }
                    else { f0 = res[cht][st][2 * rp]; f1 = res[cht][st][2 * rp + 1]; }
                    unsigned short h0 = f2bf(f0), h1 = f2bf(f1);
                    unsigned short l0 = f2bf(f0 - bf2f(h0)), l1 = f2bf(f1 - bf2f(h1));
                    int chunk = dwi >> 2, pos = dwi & 3;
                    rb[((chunk ^ sw) << 2) + pos]       = pk2(h0, h1);
                    rb[(((chunk + 4) ^ sw) << 2) + pos] = pk2(l0, l1);
                }
            }
        }
    }
    // no barrier: fc1 reads this wave's own rows only

    // ---- fc1 MFMA (bias in MFMA) + gelu + fc2 --------------------------
    short8 bhi[8], blo[8];
    #pragma unroll
    for (int nt = 0; nt < 8; ++nt) {
        bhi[nt] = *(const short8*)(w1Tg + (size_t)(nt * 16 + col) * 64 + quad * 8);
        blo[nt] = *(const short8*)(w1Tg + (size_t)(nt * 16 + col) * 64 + 32 + quad * 8);
    }
    float w2r[8];
    #pragma unroll
    for (int nt = 0; nt < 8; ++nt) w2r[nt] = w2[nt * 16 + col];
    float b2v = b2[0];
    #pragma unroll
    for (int mt = 0; mt < 4; ++mt) {
        int srow = wave * 64 + mt * 16 + col;     // A row m = lane&15
        int sw = srow & 7;
        short8 ahi = *(const short8*)(hT + srow * WP + ((quad ^ sw) << 3));
        short8 alo = *(const short8*)(hT + srow * WP + (((quad ^ sw) ^ 4) << 3));
        float part[4] = {0.f, 0.f, 0.f, 0.f};
        #pragma unroll
        for (int nt = 0; nt < 8; ++nt) {
            floatx4 a = {0.f, 0.f, 0.f, 0.f};
            a = __builtin_amdgcn_mfma_f32_16x16x32_bf16(ahi, bhi[nt], a, 0, 0, 0);
            a = __builtin_amdgcn_mfma_f32_16x16x32_bf16(ahi, blo[nt], a, 0, 0, 0);
            a = __builtin_amdgcn_mfma_f32_16x16x32_bf16(alo, bhi[nt], a, 0, 0, 0);
            #pragma unroll
            for (int r = 0; r < 4; ++r) {
                float t = gelu_fast(a[r]);
                part[r] += t * w2r[nt];
            }
        }
        #pragma unroll
        for (int r = 0; r < 4; ++r) {
            float p = row16_sum(part[r]);
            if (col == 0) {
                int row = wave * 64 + mt * 16 + quad * 4 + r;   // dead rows of this tile
                *(float*)(&hT[row * WP + ((row & 7) << 3)]) = p + b2v;
            }
        }
    }
    __syncthreads();      // the single cross-wave hand-off
    out[(size_t)b * SS + blockIdx.x * 256 + tid] = *(const float*)(&hT[tid * WP + ((tid & 7) << 3)]);
}

extern "C" void kernel_launch(void* const* d_in, const int* in_sizes, int n_in,
                              void* d_out, int out_size, void* d_ws, size_t ws_size,
                              hipStream_t stream) {
    (void)in_sizes; (void)n_in; (void)out_size; (void)ws_size;
    const float* x    = (const float*)d_in[0];
    const float* pd   = (const float*)d_in[1];
    const float* fc0w = (const float*)d_in[2];
    const float* fc0b = (const float*)d_in[3];
    const float* fc1w = (const float*)d_in[4];
    const float* fc1b = (const float*)d_in[5];
    const float* fc2w = (const float*)d_in[6];
    const float* fc2b = (const float*)d_in[7];

    char* ws = (char*)d_ws;
    unsigned* h2 = (unsigned*)ws;
    size_t off = (size_t)BB * (CC / 2) * SS * 4;                      // 83.9 MB (paired bf16)
    float* cP = (float*)(ws + off); off += (size_t)4 * NSLOT * BB * 640 * 4;  // 5.24 MB
    float* cA = (float*)(ws + off); off += (size_t)BB * CC * NM * 4;
    float* cB = (float*)(ws + off); off += (size_t)BB * CC * NM * 4;
    float* invmax = (float*)(ws + off); off += 256;
    unsigned short* w1Tg = (unsigned short*)(ws + off); off += (size_t)HH * 64 * 2;  // 16 KB
    unsigned short* Bpk  = (unsigned short*)(ws + off); off += (size_t)BB * 4096 * 2; // 256 KB
    unsigned* trigT = (unsigned*)(ws + off); off += (size_t)SS * 16 * 4;             // 4 MB
    const size_t CPL = (size_t)NSLOT * BB * 640;   // floats per layer-slot set

    dim3 gBS(SS / 256, BB);

    k_prep<<<1538, 256, 0, stream>>>(pd, fc1w, fc1b, invmax, cP, w1Tg, trigT);
    k_fc0_dft<<<gBS, 256, 0, stream>>>(x, pd, fc0w, fc0b, invmax, trigT, h2, cP);

    for (int l = 0; l < 3; ++l) {
        const float* wre = (const float*)d_in[8 + 4 * l];
        const float* wim = (const float*)d_in[9 + 4 * l];
        const float* ww  = (const float*)d_in[10 + 4 * l];
        const float* wb  = (const float*)d_in[11 + 4 * l];
        k_mix<<<BB, 320, 0, stream>>>(cP + (size_t)l * CPL, wre, wim, ww, wb, cA, cB, Bpk);
        k_point_dft<<<gBS, 256, 0, stream>>>(h2, Bpk, trigT, cP + (size_t)(l + 1) * CPL);
    }
    {   // layer 3 fused with fc1/gelu/fc2
        const float* wre = (const float*)d_in[20];
        const float* wim = (const float*)d_in[21];
        const float* ww  = (const float*)d_in[22];
        const float* wb  = (const float*)d_in[23];
        k_mix<<<BB, 320, 0, stream>>>(cP + (size_t)3 * CPL, wre, wim, ww, wb, cA, cB, Bpk);
        k_point_final<<<gBS, 256, 0, stream>>>(h2, Bpk, w1Tg, fc2w, fc2b, trigT, (float*)d_out);
    }
}